// Round 8
// baseline (242.122 us; speedup 1.0000x reference)
//
#include <hip/hip_runtime.h>
#include <hip/hip_bf16.h>

#define TBL 50
#define K 20
#define D 128
#define E 256
#define NB_B 2048
#define NSLOT (NB_B*K)     // 40960
#define G 16

typedef unsigned short ushort;
typedef unsigned short ushort8 __attribute__((ext_vector_type(8)));
typedef float f32x4 __attribute__((ext_vector_type(4)));
typedef __bf16 bf16x8 __attribute__((ext_vector_type(8)));

// ws float offsets
#define OFF_GC   0               // [l2][512] f32 (n = h*256+j)
#define OFF_U    1024            // [l2*2][128] f32
#define OFF_CC   1536            // [4] f32
#define OFF_QC   1540            // (unused, kept for layout stability)
#define OFF_PKF  2052            // packed bf16 weights (ushort region, 524288 sh)
#define OFF_NBR  264196          // [40960][128] f32
#define OFF_CNT  5507076         // int count; int compact[40960]
// ushort offsets inside PK region
#define APKo   0                 // [l2][ (nt32*4+kk)*64+lane ][8]
#define VPKo   131072            // [l2*h2][ (nt8*8+kk)*64+lane ][8]
#define OPKo   262144            // [l2][ (nt16*8+kk)*64+lane ][8]
#define W1PKo  393216            // [l2][ (nt8*12+kk)*64+lane ][8]
#define W2PKo  491520            // [l2][ (nt8*4+kk)*64+lane ][8]

__device__ __forceinline__ float cosr(float x) {
  // cos(x): compensated reduction to revolutions, |err| ~1e-6 rad for |x|<=2e5
  const float HI = 0.15915493667125702f;   // fl(1/2pi)
  const float LO = 6.4206383e-9f;          // 1/2pi - HI
  float k = rintf(x * HI);
  float f = __fmaf_rn(x, HI, -k);
  f = __fmaf_rn(x, LO, f);
  return __builtin_amdgcn_cosf(f);         // v_cos_f32 (revolutions)
}
__device__ __forceinline__ float b2f(ushort u) {
  return __uint_as_float(((unsigned)u) << 16);
}
__device__ __forceinline__ ushort cvtbf(float f) {
  unsigned u = __float_as_uint(f);
  return (ushort)((u + 0x7FFF + ((u >> 16) & 1)) >> 16);
}
__device__ __forceinline__ bf16x8 ldb8(const ushort* p) {
  union { ushort8 u; bf16x8 b; } c;
  c.u = *(const ushort8*)p;
  return c.b;
}

__global__ __launch_bounds__(256) void precompute2(
    const float* __restrict__ Wq, const float* __restrict__ Wk,
    const float* __restrict__ bq, const float* __restrict__ bk,
    const float* __restrict__ time_b, float* __restrict__ ws)
{
  __shared__ float sqc[128], ctb[128];
  int b = blockIdx.x, t = threadIdx.x;
  ushort* wsu = (ushort*)(ws + OFF_PKF);
  if (b < 512) {           // A[l][h][i][j], j = t -> APK bf16
    int l = b >> 8, h = (b >> 7) & 1, i = b & 127;
    float s = 0.f;
    const float* wq = Wq + l*65536 + h*32768 + i;
    const float* wk = Wk + l*65536 + h*32768 + t;
    for (int m = 0; m < 128; m++) s += wq[m*256]*wk[m*256];
    int N = h*256 + t;
    int nt = N >> 4, cl = N & 15;
    int kk = i >> 5, ch = (i >> 3) & 3, bb = i & 7;
    wsu[APKo + (long)l*65536 + (((nt*4+kk)*64 + ch*16 + cl)*8) + bb] = cvtbf(s);
  } else {
    int q = b - 512, l = q >> 1, h = q & 1;
    if (t < 128) ctb[t] = cosf(time_b[t]);
    __syncthreads();
    if (t < 128) {  // qc[e = h*128+t] = bq + Wq[:,128:]·cos(time_b)
      int e = h*128 + t;
      float a = bq[l*256 + e];
      const float* wq = Wq + l*65536 + e*256 + 128;
      for (int m = 0; m < 128; m++) a += wq[m]*ctb[m];
      sqc[t] = a;
    }
    __syncthreads();
    { float s = 0.f;      // gc
      const float* wk = Wk + l*65536 + h*32768 + t;
      for (int m = 0; m < 128; m++) s += sqc[m]*wk[m*256];
      ws[OFF_GC + l*512 + h*256 + t] = s; }
    if (t < 128) {        // u
      float s = 0.f;
      const float* wq = Wq + l*65536 + h*32768 + t;
      const float* bkp = bk + l*256 + h*128;
      for (int m = 0; m < 128; m++) s += wq[m*256]*bkp[m];
      ws[OFF_U + (l*2+h)*128 + t] = s; }
    if (t == 254) {       // cc
      float s = 0.f;
      const float* bkp = bk + l*256 + h*128;
      for (int m = 0; m < 128; m++) s += sqc[m]*bkp[m];
      ws[OFF_CC + l*2+h] = s; }
  }
}

__global__ __launch_bounds__(256) void packw(
    const float* __restrict__ Wv, const float* __restrict__ Wo,
    const float* __restrict__ W1, const float* __restrict__ W2,
    float* __restrict__ ws)
{
  int idx = blockIdx.x*256 + threadIdx.x;   // < 393216
  ushort* wsu = (ushort*)(ws + OFF_PKF);
  if (idx == 0) *(int*)(ws + OFF_CNT) = 0;  // counter reset (compact runs next)
  if (idx < 131072) {          // VPK
    int q = idx >> 15, r = idx & 32767, l = q >> 1, h = q & 1;
    int bb = r & 7, lane = (r >> 3) & 63, kk = (r >> 9) & 7, nt = r >> 12;
    int k = kk*32 + (lane>>4)*8 + bb, d = nt*16 + (lane&15);
    wsu[VPKo + idx] = cvtbf(Wv[l*65536 + (h*128+d)*256 + k]);
  } else if (idx < 262144) {   // OPK
    int rel = idx - 131072, l = rel >> 16, r = rel & 65535;
    int bb = r & 7, lane = (r >> 3) & 63, kk = (r >> 9) & 7, nt = r >> 12;
    int k = kk*32 + (lane>>4)*8 + bb, e = nt*16 + (lane&15);
    wsu[OPKo + rel] = cvtbf(Wo[l*65536 + e*256 + k]);
  } else if (idx < 360448) {   // W1PK
    int rel = idx - 262144, l = rel / 49152, r = rel % 49152;
    int nt = r / 6144, rr = r - nt*6144;
    int kk = rr >> 9, lane = (rr >> 3) & 63, bb = rr & 7;
    int k = kk*32 + (lane>>4)*8 + bb, d = nt*16 + (lane&15);
    wsu[W1PKo + rel] = cvtbf(W1[l*49152 + d*384 + k]);
  } else {                     // W2PK
    int rel = idx - 360448, l = rel >> 14, r = rel & 16383;
    int nt = r >> 11, rr = r & 2047;
    int kk = rr >> 9, lane = (rr >> 3) & 63, bb = rr & 7;
    int k = kk*32 + (lane>>4)*8 + bb, d = nt*16 + (lane&15);
    wsu[W2PKo + rel] = cvtbf(W2[l*16384 + d*128 + k]);
  }
}

__global__ __launch_bounds__(256) void compact_valid(
    const int* __restrict__ edges, const int* __restrict__ u_mask,
    float* __restrict__ ws)
{
  int idx = blockIdx.x*256 + threadIdx.x;    // < 40960
  int b = idx / K, s = idx - b*K;
  int pe = edges[b];
  if (u_mask[pe*TBL + (TBL-K) + s] > 0) {
    int pos = atomicAdd((int*)(ws + OFF_CNT), 1);
    ((int*)(ws + OFF_CNT))[1 + pos] = idx;
  }
}

template<int LAYER>
__global__ __launch_bounds__(256, 4) void attend(
    const int* __restrict__ nodes, const int* __restrict__ edges, const int* __restrict__ tstamps,
    const int* __restrict__ u_edges, const int* __restrict__ u_neig,
    const int* __restrict__ u_times, const int* __restrict__ u_mask,
    const int* __restrict__ i_neig, const int* __restrict__ i_times, const int* __restrict__ i_mask,
    const float* __restrict__ user_emb, const float* __restrict__ item_emb,
    const float* __restrict__ time_w, const float* __restrict__ time_b,
    const float* __restrict__ bv, const float* __restrict__ bo,
    const float* __restrict__ b1, const float* __restrict__ b2,
    float* __restrict__ wsf, float* __restrict__ out)
{
  // sOP2 rows [n][392]: cols 0..255 = o -> oo -> h1 (time-multiplexed), 256..383 = feat
  __shared__ __align__(16) ushort sOP2[16*392];
  __shared__ __align__(16) ushort sGWS[16*520];  // g then wsum [h*256+j]
  __shared__ float sTW[128], sTB[128], sAL[640], sQB[32];
  __shared__ int imem[96];   // 0 nid,16 ntime,32 erow,48 slot,64 anyv,80 act
  __shared__ int nbm[960];   // [0:320) row, [320:640) time, [640:960) mask

  const int tid = threadIdx.x, blk = blockIdx.x, l = LAYER;
  const int lane = tid & 63, wv = tid >> 6;
  const int col = lane & 15, chunk = lane >> 4;
  const ushort* wsu = (const ushort*)(wsf + OFF_PKF);

  int count = (LAYER == 0) ? *(const int*)(wsf + OFF_CNT) : NB_B;
  if (blk*G >= count) return;

  if (tid < G) {
    int idx = blk*G + tid; int act = idx < count ? 1 : 0;
    int slot, nid, ntm, erow;
    if (LAYER == 0) {
      int ii = act ? idx : 0;
      slot = ((const int*)(wsf + OFF_CNT))[1 + ii];
      int bb = slot / K, s = slot - bb*K;
      int base = edges[bb]*TBL + (TBL-K) + s;
      nid = u_neig[base]; ntm = u_times[base]; erow = u_edges[base];
    } else { slot = idx; nid = nodes[idx]; ntm = tstamps[idx]; erow = edges[idx]; }
    imem[tid] = nid; imem[16+tid] = ntm; imem[32+tid] = erow;
    imem[48+tid] = slot; imem[80+tid] = act;
  }
  if (tid < 128) { sTW[tid] = time_w[tid]; sTB[tid] = time_b[tid]; }
  __syncthreads();

  // P0: gather feat -> OP2 cols 256..383 (bf16); neighbor meta
  const float* nemb = (LAYER == 0) ? item_emb : user_emb;
  #pragma unroll
  for (int it = 0; it < 8; it++) {
    int idx = tid + it*256, n = idx >> 7, i = idx & 127;
    sOP2[n*392 + 256 + i] = cvtbf(nemb[(long)imem[n]*D + i]);
  }
  #pragma unroll
  for (int it = 0; it < 2; it++) {
    int p = tid + it*256;
    if (p < G*K) {
      int n = p / K, k = p - n*K;
      int base = imem[32+n]*TBL + (TBL-K) + k;
      if (LAYER == 0) { nbm[p] = i_neig[base]; nbm[320+p] = i_times[base]; nbm[640+p] = i_mask[base]; }
      else            { nbm[p] = (blk*G+n)*K + k; nbm[320+p] = u_times[base]; nbm[640+p] = u_mask[base]; }
    }
  }
  __syncthreads();

  // G1: g[16x512] = feat[16x128] @ A  (+gc), -> sGWS bf16
  {
    bf16x8 a[4];
    #pragma unroll
    for (int kk = 0; kk < 4; kk++)
      a[kk] = ldb8(&sOP2[col*392 + 256 + kk*32 + chunk*8]);
    f32x4 acc[8];
    #pragma unroll
    for (int t = 0; t < 8; t++) acc[t] = (f32x4){0.f,0.f,0.f,0.f};
    const ushort* BP = wsu + APKo + (long)l*65536;
    #pragma unroll
    for (int t = 0; t < 8; t++) {
      int nt = wv*8 + t;
      #pragma unroll
      for (int kk = 0; kk < 4; kk++) {
        bf16x8 b = ldb8(&BP[((nt*4+kk)*64 + lane)*8]);
        acc[t] = __builtin_amdgcn_mfma_f32_16x16x32_bf16(a[kk], b, acc[t], 0, 0, 0);
      }
    }
    #pragma unroll
    for (int t = 0; t < 8; t++) {
      int N = (wv*8+t)*16 + col;
      float gcv = wsf[OFF_GC + l*512 + N];
      #pragma unroll
      for (int r = 0; r < 4; r++)
        sGWS[(chunk*4+r)*520 + N] = cvtbf(acc[t][r] + gcv);
    }
  }
  if (tid < 32) {   // qb[n][h]
    int n = tid >> 1, h = tid & 1;
    float s = wsf[OFF_CC + l*2 + h];
    const float* u = wsf + OFF_U + (l*2+h)*128;
    for (int i = 0; i < 128; i++) s += b2f(sOP2[n*392 + 256 + i])*u[i];
    sQB[tid] = s;
  }
  __syncthreads();

  const float* nbfeat = (LAYER == 0) ? user_emb : (wsf + OFF_NBR);

  // Phase A: 320 scores, balanced 80/wave
  {
    auto scoreItem = [&](int p) {
      int n = p / K, k = p - n*K;
      float dtf = (float)(imem[16+n] - nbm[320+p]);
      const float4* fr = (const float4*)(nbfeat + (long)nbm[p]*D);
      const ushort8* gp = (const ushort8*)&sGWS[n*520];
      float a0 = 0.f, a1 = 0.f;
      #pragma unroll 4
      for (int c = 0; c < 16; c++) {
        float4 f0 = fr[2*c], f1 = fr[2*c+1];
        ushort8 g0 = gp[c], g1 = gp[32+c];
        a0 += f0.x*b2f(g0[0]) + f0.y*b2f(g0[1]) + f0.z*b2f(g0[2]) + f0.w*b2f(g0[3])
            + f1.x*b2f(g0[4]) + f1.y*b2f(g0[5]) + f1.z*b2f(g0[6]) + f1.w*b2f(g0[7]);
        a1 += f0.x*b2f(g1[0]) + f0.y*b2f(g1[1]) + f0.z*b2f(g1[2]) + f0.w*b2f(g1[3])
            + f1.x*b2f(g1[4]) + f1.y*b2f(g1[5]) + f1.z*b2f(g1[6]) + f1.w*b2f(g1[7]);
      }
      #pragma unroll 2
      for (int c = 0; c < 16; c++) {
        ushort8 g0 = gp[16+c], g1 = gp[48+c];
        float a0c = 0.f, a1c = 0.f;
        #pragma unroll
        for (int j = 0; j < 8; j++) {
          float cv = cosr(__fadd_rn(__fmul_rn(dtf, sTW[c*8+j]), sTB[c*8+j]));
          a0c += cv*b2f(g0[j]); a1c += cv*b2f(g1[j]);
        }
        a0 += a0c; a1 += a1c;
      }
      int m = nbm[640+p];
      const float invsq = 0.08838834764831845f;
      sAL[n*40 + k]      = m > 0 ? (a0 + sQB[n*2])*invsq   : -1e9f;
      sAL[n*40 + 20 + k] = m > 0 ? (a1 + sQB[n*2+1])*invsq : -1e9f;
    };
    scoreItem(wv*80 + lane);
    if (lane < 16) scoreItem(wv*80 + 64 + lane);
  }
  __syncthreads();

  // softmax
  if (tid < 2*G) {
    int n = tid >> 1, h = tid & 1;
    float* a = &sAL[n*40 + h*20];
    float mx = -1e30f;
    for (int k = 0; k < K; k++) mx = fmaxf(mx, a[k]);
    float s = 0.f;
    for (int k = 0; k < K; k++) { float e = __expf(a[k]-mx); a[k] = e; s += e; }
    float inv = 1.f/s;
    for (int k = 0; k < K; k++) a[k] *= inv;
    if (h == 0) { int any = 0;
      for (int k = 0; k < K; k++) any |= nbm[640 + n*20 + k];
      imem[64+n] = any; }
  }
  __syncthreads();

  // Phase C: wsum -> sGWS bf16 rows [n][h*256+j]
  {
    const int n = tid >> 4, e0 = tid & 15;
    float a0r[K], a1r[K], dtr[K]; int rowr[K];
    #pragma unroll
    for (int k = 0; k < K; k++) {
      a0r[k] = sAL[n*40 + k]; a1r[k] = sAL[n*40 + 20 + k];
      dtr[k] = (float)(imem[16+n] - nbm[320 + n*20 + k]);
      rowr[k] = nbm[n*20 + k];
    }
    #pragma unroll
    for (int it = 0; it < 8; it++) {
      int e = e0 + it*16;
      float w0 = 0.f, w1 = 0.f;
      #pragma unroll
      for (int k = 0; k < K; k++) {
        float f = nbfeat[(long)rowr[k]*D + e];
        w0 += a0r[k]*f; w1 += a1r[k]*f;
      }
      sGWS[n*520 + e]       = cvtbf(w0);
      sGWS[n*520 + 256 + e] = cvtbf(w1);
    }
    #pragma unroll
    for (int it = 0; it < 8; it++) {
      int jj = e0 + it*16;
      float twj = sTW[jj], tbj = sTB[jj];
      float w0 = 0.f, w1 = 0.f;
      #pragma unroll
      for (int k = 0; k < K; k++) {
        float c = cosr(__fadd_rn(__fmul_rn(dtr[k], twj), tbj));
        w0 += a0r[k]*c; w1 += a1r[k]*c;
      }
      sGWS[n*520 + 128 + jj] = cvtbf(w0);
      sGWS[n*520 + 384 + jj] = cvtbf(w1);
    }
  }
  __syncthreads();

  // G2: o = wsum_h @ Wv_h (+bv) -> sOP2 cols 0..255 (dead region)
  {
    int h = wv >> 1, ntb = (wv & 1)*4;
    bf16x8 a[8];
    #pragma unroll
    for (int kk = 0; kk < 8; kk++)
      a[kk] = ldb8(&sGWS[col*520 + h*256 + kk*32 + chunk*8]);
    f32x4 acc[4];
    #pragma unroll
    for (int t = 0; t < 4; t++) acc[t] = (f32x4){0.f,0.f,0.f,0.f};
    const ushort* BP = wsu + VPKo + (long)(l*2+h)*32768;
    #pragma unroll
    for (int t = 0; t < 4; t++) {
      int nt = ntb + t;
      #pragma unroll
      for (int kk = 0; kk < 8; kk++) {
        bf16x8 b = ldb8(&BP[((nt*8+kk)*64 + lane)*8]);
        acc[t] = __builtin_amdgcn_mfma_f32_16x16x32_bf16(a[kk], b, acc[t], 0, 0, 0);
      }
    }
    #pragma unroll
    for (int t = 0; t < 4; t++) {
      int ocol = h*128 + (ntb+t)*16 + col;
      float bb = bv[l*256 + ocol];
      #pragma unroll
      for (int r = 0; r < 4; r++)
        sOP2[(chunk*4+r)*392 + ocol] = cvtbf(acc[t][r] + bb);
    }
  }
  __syncthreads();

  // G3: oo = o @ Wo (+bo, anyv mask) -> sOP2 cols 0..255 (in-place via pre-load + barrier)
  {
    bf16x8 a[8];
    #pragma unroll
    for (int kk = 0; kk < 8; kk++)
      a[kk] = ldb8(&sOP2[col*392 + kk*32 + chunk*8]);
    __syncthreads();   // all o-frags read before oo overwrites
    f32x4 acc[4];
    #pragma unroll
    for (int t = 0; t < 4; t++) acc[t] = (f32x4){0.f,0.f,0.f,0.f};
    const ushort* BP = wsu + OPKo + (long)l*65536;
    #pragma unroll
    for (int t = 0; t < 4; t++) {
      int nt = wv*4 + t;
      #pragma unroll
      for (int kk = 0; kk < 8; kk++) {
        bf16x8 b = ldb8(&BP[((nt*8+kk)*64 + lane)*8]);
        acc[t] = __builtin_amdgcn_mfma_f32_16x16x32_bf16(a[kk], b, acc[t], 0, 0, 0);
      }
    }
    #pragma unroll
    for (int t = 0; t < 4; t++) {
      int e = (wv*4+t)*16 + col;
      float bb = bo[l*256 + e];
      #pragma unroll
      for (int r = 0; r < 4; r++) {
        int row = chunk*4 + r;
        float v = imem[64+row] ? (acc[t][r] + bb) : 0.f;
        sOP2[row*392 + e] = cvtbf(v);
      }
    }
  }
  __syncthreads();

  // G4: h1 = [oo,feat] @ W1 (+b1, relu) -> sOP2 cols 0..127
  {
    bf16x8 a[12];
    #pragma unroll
    for (int kk = 0; kk < 12; kk++)
      a[kk] = ldb8(&sOP2[col*392 + kk*32 + chunk*8]);
    __syncthreads();   // all oo/feat frags read before h1 overwrites
    f32x4 acc[2];
    acc[0] = (f32x4){0.f,0.f,0.f,0.f}; acc[1] = (f32x4){0.f,0.f,0.f,0.f};
    const ushort* BP = wsu + W1PKo + (long)l*49152;
    #pragma unroll
    for (int t = 0; t < 2; t++) {
      int nt = wv*2 + t;
      #pragma unroll
      for (int kk = 0; kk < 12; kk++) {
        bf16x8 b = ldb8(&BP[((nt*12+kk)*64 + lane)*8]);
        acc[t] = __builtin_amdgcn_mfma_f32_16x16x32_bf16(a[kk], b, acc[t], 0, 0, 0);
      }
    }
    #pragma unroll
    for (int t = 0; t < 2; t++) {
      int dcol = (wv*2+t)*16 + col;
      float bb = b1[l*128 + dcol];
      #pragma unroll
      for (int r = 0; r < 4; r++)
        sOP2[(chunk*4+r)*392 + dcol] = cvtbf(fmaxf(acc[t][r] + bb, 0.f));
    }
  }
  __syncthreads();

  // G5: out = h1 @ W2 (+b2) -> global f32
  {
    bf16x8 a[4];
    #pragma unroll
    for (int kk = 0; kk < 4; kk++)
      a[kk] = ldb8(&sOP2[col*392 + kk*32 + chunk*8]);
    f32x4 acc[2];
    acc[0] = (f32x4){0.f,0.f,0.f,0.f}; acc[1] = (f32x4){0.f,0.f,0.f,0.f};
    const ushort* BP = wsu + W2PKo + (long)l*16384;
    #pragma unroll
    for (int t = 0; t < 2; t++) {
      int nt = wv*2 + t;
      #pragma unroll
      for (int kk = 0; kk < 4; kk++) {
        bf16x8 b = ldb8(&BP[((nt*4+kk)*64 + lane)*8]);
        acc[t] = __builtin_amdgcn_mfma_f32_16x16x32_bf16(a[kk], b, acc[t], 0, 0, 0);
      }
    }
    #pragma unroll
    for (int t = 0; t < 2; t++) {
      int dcol = (wv*2+t)*16 + col;
      float bb = b2[l*128 + dcol];
      #pragma unroll
      for (int r = 0; r < 4; r++) {
        int row = chunk*4 + r;
        float v = acc[t][r] + bb;
        if (LAYER == 0) { if (imem[80+row]) wsf[OFF_NBR + (long)imem[48+row]*D + dcol] = v; }
        else            out[(long)(blk*G + row)*D + dcol] = v;
      }
    }
  }
}

extern "C" void kernel_launch(void* const* d_in, const int* in_sizes, int n_in,
                              void* d_out, int out_size, void* d_ws, size_t ws_size,
                              hipStream_t stream) {
  const int* nodes  = (const int*)d_in[0];
  const int* edges  = (const int*)d_in[1];
  const int* tst    = (const int*)d_in[2];
  const int* u_neig = (const int*)d_in[4];
  const int* u_edges= (const int*)d_in[5];
  const int* u_times= (const int*)d_in[6];
  const int* u_mask = (const int*)d_in[7];
  const int* i_neig = (const int*)d_in[8];
  const int* i_times= (const int*)d_in[10];
  const int* i_mask = (const int*)d_in[11];
  const float* user_emb = (const float*)d_in[12];
  const float* item_emb = (const float*)d_in[13];
  const float* time_w = (const float*)d_in[14];
  const float* time_b = (const float*)d_in[15];
  const float* Wq = (const float*)d_in[16]; const float* bq = (const float*)d_in[17];
  const float* Wk = (const float*)d_in[18]; const float* bk = (const float*)d_in[19];
  const float* Wv = (const float*)d_in[20]; const float* bv = (const float*)d_in[21];
  const float* Wo = (const float*)d_in[22]; const float* bo = (const float*)d_in[23];
  const float* W1 = (const float*)d_in[24]; const float* b1 = (const float*)d_in[25];
  const float* W2 = (const float*)d_in[26]; const float* b2 = (const float*)d_in[27];
  float* ws = (float*)d_ws;
  float* out = (float*)d_out;

  precompute2<<<dim3(516), dim3(256), 0, stream>>>(Wq, Wk, bq, bk, time_b, ws);
  packw<<<dim3(1536), dim3(256), 0, stream>>>(Wv, Wo, W1, W2, ws);
  compact_valid<<<dim3(160), dim3(256), 0, stream>>>(edges, u_mask, ws);

  attend<0><<<dim3(NSLOT/G), dim3(256), 0, stream>>>(
      nodes, edges, tst, u_edges, u_neig, u_times, u_mask,
      i_neig, i_times, i_mask, user_emb, item_emb, time_w, time_b,
      bv, bo, b1, b2, ws, out);

  attend<1><<<dim3(NB_B/G), dim3(256), 0, stream>>>(
      nodes, edges, tst, u_edges, u_neig, u_times, u_mask,
      i_neig, i_times, i_mask, user_emb, item_emb, time_w, time_b,
      bv, bo, b1, b2, ws, out);
}

// Round 9
// 240.016 us; speedup vs baseline: 1.0088x; 1.0088x over previous
//
#include <hip/hip_runtime.h>
#include <hip/hip_bf16.h>

#define TBL 50
#define K 20
#define D 128
#define E 256
#define NB_B 2048
#define NSLOT (NB_B*K)     // 40960
#define G 16

typedef unsigned short ushort;
typedef unsigned short ushort8 __attribute__((ext_vector_type(8)));
typedef float f32x4 __attribute__((ext_vector_type(4)));
typedef __bf16 bf16x8 __attribute__((ext_vector_type(8)));

// ws float offsets
#define OFF_GC   0               // [l2][512] f32 (n = h*256+j)
#define OFF_U    1024            // [l2*2][128] f32
#define OFF_CC   1536            // [4] f32
#define OFF_QC   1540            // (unused, kept for layout stability)
#define OFF_PKF  2052            // packed bf16 weights (ushort region, 524288 sh)
#define OFF_NBR  264196          // [40960][128] f32
#define OFF_CNT  5507076         // int count; int compact[40960]
// ushort offsets inside PK region
#define APKo   0                 // [l2][ (nt32*4+kk)*64+lane ][8]
#define VPKo   131072            // [l2*h2][ (nt8*8+kk)*64+lane ][8]
#define OPKo   262144            // [l2][ (nt16*8+kk)*64+lane ][8]
#define W1PKo  393216            // [l2][ (nt8*12+kk)*64+lane ][8]
#define W2PKo  491520            // [l2][ (nt8*4+kk)*64+lane ][8]

__device__ __forceinline__ float cosr(float x) {
  // cos(x): compensated reduction to revolutions, |err| ~1e-6 rad for |x|<=2e5
  const float HI = 0.15915493667125702f;   // fl(1/2pi)
  const float LO = 6.4206383e-9f;          // 1/2pi - HI
  float k = rintf(x * HI);
  float f = __fmaf_rn(x, HI, -k);
  f = __fmaf_rn(x, LO, f);
  return __builtin_amdgcn_cosf(f);         // v_cos_f32 (revolutions)
}
__device__ __forceinline__ float b2f(ushort u) {
  return __uint_as_float(((unsigned)u) << 16);
}
__device__ __forceinline__ ushort cvtbf(float f) {
  unsigned u = __float_as_uint(f);
  return (ushort)((u + 0x7FFF + ((u >> 16) & 1)) >> 16);
}
__device__ __forceinline__ bf16x8 ldb8(const ushort* p) {
  union { ushort8 u; bf16x8 b; } c;
  c.u = *(const ushort8*)p;
  return c.b;
}

__global__ __launch_bounds__(256) void precompute2(
    const float* __restrict__ Wq, const float* __restrict__ Wk,
    const float* __restrict__ bq, const float* __restrict__ bk,
    const float* __restrict__ time_b, float* __restrict__ ws)
{
  __shared__ float sqc[128], ctb[128];
  int b = blockIdx.x, t = threadIdx.x;
  ushort* wsu = (ushort*)(ws + OFF_PKF);
  if (b < 512) {           // A[l][h][i][j], j = t -> APK bf16
    int l = b >> 8, h = (b >> 7) & 1, i = b & 127;
    float s = 0.f;
    const float* wq = Wq + l*65536 + h*32768 + i;
    const float* wk = Wk + l*65536 + h*32768 + t;
    for (int m = 0; m < 128; m++) s += wq[m*256]*wk[m*256];
    int N = h*256 + t;
    int nt = N >> 4, cl = N & 15;
    int kk = i >> 5, ch = (i >> 3) & 3, bb = i & 7;
    wsu[APKo + (long)l*65536 + (((nt*4+kk)*64 + ch*16 + cl)*8) + bb] = cvtbf(s);
  } else {
    int q = b - 512, l = q >> 1, h = q & 1;
    if (t < 128) ctb[t] = cosf(time_b[t]);
    __syncthreads();
    if (t < 128) {  // qc[e = h*128+t] = bq + Wq[:,128:]·cos(time_b)
      int e = h*128 + t;
      float a = bq[l*256 + e];
      const float* wq = Wq + l*65536 + e*256 + 128;
      for (int m = 0; m < 128; m++) a += wq[m]*ctb[m];
      sqc[t] = a;
    }
    __syncthreads();
    { float s = 0.f;      // gc
      const float* wk = Wk + l*65536 + h*32768 + t;
      for (int m = 0; m < 128; m++) s += sqc[m]*wk[m*256];
      ws[OFF_GC + l*512 + h*256 + t] = s; }
    if (t < 128) {        // u
      float s = 0.f;
      const float* wq = Wq + l*65536 + h*32768 + t;
      const float* bkp = bk + l*256 + h*128;
      for (int m = 0; m < 128; m++) s += wq[m*256]*bkp[m];
      ws[OFF_U + (l*2+h)*128 + t] = s; }
    if (t == 254) {       // cc
      float s = 0.f;
      const float* bkp = bk + l*256 + h*128;
      for (int m = 0; m < 128; m++) s += sqc[m]*bkp[m];
      ws[OFF_CC + l*2+h] = s; }
  }
}

__global__ __launch_bounds__(256) void packw(
    const float* __restrict__ Wv, const float* __restrict__ Wo,
    const float* __restrict__ W1, const float* __restrict__ W2,
    float* __restrict__ ws)
{
  int idx = blockIdx.x*256 + threadIdx.x;   // < 393216
  ushort* wsu = (ushort*)(ws + OFF_PKF);
  if (idx == 0) *(int*)(ws + OFF_CNT) = 0;  // counter reset (compact runs next)
  if (idx < 131072) {          // VPK
    int q = idx >> 15, r = idx & 32767, l = q >> 1, h = q & 1;
    int bb = r & 7, lane = (r >> 3) & 63, kk = (r >> 9) & 7, nt = r >> 12;
    int k = kk*32 + (lane>>4)*8 + bb, d = nt*16 + (lane&15);
    wsu[VPKo + idx] = cvtbf(Wv[l*65536 + (h*128+d)*256 + k]);
  } else if (idx < 262144) {   // OPK
    int rel = idx - 131072, l = rel >> 16, r = rel & 65535;
    int bb = r & 7, lane = (r >> 3) & 63, kk = (r >> 9) & 7, nt = r >> 12;
    int k = kk*32 + (lane>>4)*8 + bb, e = nt*16 + (lane&15);
    wsu[OPKo + rel] = cvtbf(Wo[l*65536 + e*256 + k]);
  } else if (idx < 360448) {   // W1PK
    int rel = idx - 262144, l = rel / 49152, r = rel % 49152;
    int nt = r / 6144, rr = r - nt*6144;
    int kk = rr >> 9, lane = (rr >> 3) & 63, bb = rr & 7;
    int k = kk*32 + (lane>>4)*8 + bb, d = nt*16 + (lane&15);
    wsu[W1PKo + rel] = cvtbf(W1[l*49152 + d*384 + k]);
  } else {                     // W2PK
    int rel = idx - 360448, l = rel >> 14, r = rel & 16383;
    int nt = r >> 11, rr = r & 2047;
    int kk = rr >> 9, lane = (rr >> 3) & 63, bb = rr & 7;
    int k = kk*32 + (lane>>4)*8 + bb, d = nt*16 + (lane&15);
    wsu[W2PKo + rel] = cvtbf(W2[l*16384 + d*128 + k]);
  }
}

__global__ __launch_bounds__(256) void compact_valid(
    const int* __restrict__ edges, const int* __restrict__ u_mask,
    float* __restrict__ ws)
{
  int idx = blockIdx.x*256 + threadIdx.x;    // < 40960
  int b = idx / K, s = idx - b*K;
  int pe = edges[b];
  if (u_mask[pe*TBL + (TBL-K) + s] > 0) {
    int pos = atomicAdd((int*)(ws + OFF_CNT), 1);
    ((int*)(ws + OFF_CNT))[1 + pos] = idx;
  }
}

template<int LAYER>
__global__ __launch_bounds__(256, 3) void attend(
    const int* __restrict__ nodes, const int* __restrict__ edges, const int* __restrict__ tstamps,
    const int* __restrict__ u_edges, const int* __restrict__ u_neig,
    const int* __restrict__ u_times, const int* __restrict__ u_mask,
    const int* __restrict__ i_neig, const int* __restrict__ i_times, const int* __restrict__ i_mask,
    const float* __restrict__ user_emb, const float* __restrict__ item_emb,
    const float* __restrict__ time_w, const float* __restrict__ time_b,
    const float* __restrict__ bv, const float* __restrict__ bo,
    const float* __restrict__ b1, const float* __restrict__ b2,
    float* __restrict__ wsf, float* __restrict__ out)
{
  // sOP2 rows [n][392]: cols 0..255 = o -> oo -> h1 (time-multiplexed), 256..383 = feat
  __shared__ __align__(16) ushort sOP2[16*392];
  __shared__ __align__(16) ushort sGWS[16*520];  // g then wsum [h*256+j]
  __shared__ float sTW[128], sTB[128], sAL[640], sQB[32];
  __shared__ int imem[96];   // 0 nid,16 ntime,32 erow,48 slot,64 anyv,80 act
  __shared__ int nbm[960];   // [0:320) row, [320:640) time, [640:960) mask

  const int tid = threadIdx.x, blk = blockIdx.x, l = LAYER;
  const int lane = tid & 63, wv = tid >> 6;
  const int col = lane & 15, chunk = lane >> 4;
  const ushort* wsu = (const ushort*)(wsf + OFF_PKF);

  int count = (LAYER == 0) ? *(const int*)(wsf + OFF_CNT) : NB_B;
  if (blk*G >= count) return;

  if (tid < G) {
    int idx = blk*G + tid; int act = idx < count ? 1 : 0;
    int slot, nid, ntm, erow;
    if (LAYER == 0) {
      int ii = act ? idx : 0;
      slot = ((const int*)(wsf + OFF_CNT))[1 + ii];
      int bb = slot / K, s = slot - bb*K;
      int base = edges[bb]*TBL + (TBL-K) + s;
      nid = u_neig[base]; ntm = u_times[base]; erow = u_edges[base];
    } else { slot = idx; nid = nodes[idx]; ntm = tstamps[idx]; erow = edges[idx]; }
    imem[tid] = nid; imem[16+tid] = ntm; imem[32+tid] = erow;
    imem[48+tid] = slot; imem[80+tid] = act;
  }
  if (tid < 128) { sTW[tid] = time_w[tid]; sTB[tid] = time_b[tid]; }
  __syncthreads();

  // P0: gather feat -> OP2 cols 256..383 (bf16); neighbor meta
  const float* nemb = (LAYER == 0) ? item_emb : user_emb;
  #pragma unroll
  for (int it = 0; it < 8; it++) {
    int idx = tid + it*256, n = idx >> 7, i = idx & 127;
    sOP2[n*392 + 256 + i] = cvtbf(nemb[(long)imem[n]*D + i]);
  }
  #pragma unroll
  for (int it = 0; it < 2; it++) {
    int p = tid + it*256;
    if (p < G*K) {
      int n = p / K, k = p - n*K;
      int base = imem[32+n]*TBL + (TBL-K) + k;
      if (LAYER == 0) { nbm[p] = i_neig[base]; nbm[320+p] = i_times[base]; nbm[640+p] = i_mask[base]; }
      else            { nbm[p] = (blk*G+n)*K + k; nbm[320+p] = u_times[base]; nbm[640+p] = u_mask[base]; }
    }
  }
  __syncthreads();

  // G1: g[16x512] = feat[16x128] @ A  (+gc), -> sGWS bf16
  {
    bf16x8 a[4];
    #pragma unroll
    for (int kk = 0; kk < 4; kk++)
      a[kk] = ldb8(&sOP2[col*392 + 256 + kk*32 + chunk*8]);
    f32x4 acc[8];
    #pragma unroll
    for (int t = 0; t < 8; t++) acc[t] = (f32x4){0.f,0.f,0.f,0.f};
    const ushort* BP = wsu + APKo + (long)l*65536;
    #pragma unroll
    for (int t = 0; t < 8; t++) {
      int nt = wv*8 + t;
      #pragma unroll
      for (int kk = 0; kk < 4; kk++) {
        bf16x8 b = ldb8(&BP[((nt*4+kk)*64 + lane)*8]);
        acc[t] = __builtin_amdgcn_mfma_f32_16x16x32_bf16(a[kk], b, acc[t], 0, 0, 0);
      }
    }
    #pragma unroll
    for (int t = 0; t < 8; t++) {
      int N = (wv*8+t)*16 + col;
      float gcv = wsf[OFF_GC + l*512 + N];
      #pragma unroll
      for (int r = 0; r < 4; r++)
        sGWS[(chunk*4+r)*520 + N] = cvtbf(acc[t][r] + gcv);
    }
  }
  if (tid < 32) {   // qb[n][h]
    int n = tid >> 1, h = tid & 1;
    float s = wsf[OFF_CC + l*2 + h];
    const float* u = wsf + OFF_U + (l*2+h)*128;
    for (int i = 0; i < 128; i++) s += b2f(sOP2[n*392 + 256 + i])*u[i];
    sQB[tid] = s;
  }
  __syncthreads();

  const float* nbfeat = (LAYER == 0) ? user_emb : (wsf + OFF_NBR);

  // Phase A: 320 scores, balanced 80/wave
  {
    auto scoreItem = [&](int p) {
      int n = p / K, k = p - n*K;
      float dtf = (float)(imem[16+n] - nbm[320+p]);
      const float4* fr = (const float4*)(nbfeat + (long)nbm[p]*D);
      const ushort8* gp = (const ushort8*)&sGWS[n*520];
      float a0 = 0.f, a1 = 0.f;
      #pragma unroll 4
      for (int c = 0; c < 16; c++) {
        float4 f0 = fr[2*c], f1 = fr[2*c+1];
        ushort8 g0 = gp[c], g1 = gp[32+c];
        a0 += f0.x*b2f(g0[0]) + f0.y*b2f(g0[1]) + f0.z*b2f(g0[2]) + f0.w*b2f(g0[3])
            + f1.x*b2f(g0[4]) + f1.y*b2f(g0[5]) + f1.z*b2f(g0[6]) + f1.w*b2f(g0[7]);
        a1 += f0.x*b2f(g1[0]) + f0.y*b2f(g1[1]) + f0.z*b2f(g1[2]) + f0.w*b2f(g1[3])
            + f1.x*b2f(g1[4]) + f1.y*b2f(g1[5]) + f1.z*b2f(g1[6]) + f1.w*b2f(g1[7]);
      }
      #pragma unroll 2
      for (int c = 0; c < 16; c++) {
        ushort8 g0 = gp[16+c], g1 = gp[48+c];
        float a0c = 0.f, a1c = 0.f;
        #pragma unroll
        for (int j = 0; j < 8; j++) {
          float cv = cosr(__fadd_rn(__fmul_rn(dtf, sTW[c*8+j]), sTB[c*8+j]));
          a0c += cv*b2f(g0[j]); a1c += cv*b2f(g1[j]);
        }
        a0 += a0c; a1 += a1c;
      }
      int m = nbm[640+p];
      const float invsq = 0.08838834764831845f;
      sAL[n*40 + k]      = m > 0 ? (a0 + sQB[n*2])*invsq   : -1e9f;
      sAL[n*40 + 20 + k] = m > 0 ? (a1 + sQB[n*2+1])*invsq : -1e9f;
    };
    scoreItem(wv*80 + lane);
    if (lane < 16) scoreItem(wv*80 + 64 + lane);
  }
  __syncthreads();

  // softmax
  if (tid < 2*G) {
    int n = tid >> 1, h = tid & 1;
    float* a = &sAL[n*40 + h*20];
    float mx = -1e30f;
    for (int k = 0; k < K; k++) mx = fmaxf(mx, a[k]);
    float s = 0.f;
    for (int k = 0; k < K; k++) { float e = __expf(a[k]-mx); a[k] = e; s += e; }
    float inv = 1.f/s;
    for (int k = 0; k < K; k++) a[k] *= inv;
    if (h == 0) { int any = 0;
      for (int k = 0; k < K; k++) any |= nbm[640 + n*20 + k];
      imem[64+n] = any; }
  }
  __syncthreads();

  // Phase C: wsum -> sGWS bf16 rows [n][h*256+j]
  {
    const int n = tid >> 4, e0 = tid & 15;
    float a0r[K], a1r[K], dtr[K]; int rowr[K];
    #pragma unroll
    for (int k = 0; k < K; k++) {
      a0r[k] = sAL[n*40 + k]; a1r[k] = sAL[n*40 + 20 + k];
      dtr[k] = (float)(imem[16+n] - nbm[320 + n*20 + k]);
      rowr[k] = nbm[n*20 + k];
    }
    #pragma unroll
    for (int it = 0; it < 8; it++) {
      int e = e0 + it*16;
      float w0 = 0.f, w1 = 0.f;
      #pragma unroll
      for (int k = 0; k < K; k++) {
        float f = nbfeat[(long)rowr[k]*D + e];
        w0 += a0r[k]*f; w1 += a1r[k]*f;
      }
      sGWS[n*520 + e]       = cvtbf(w0);
      sGWS[n*520 + 256 + e] = cvtbf(w1);
    }
    #pragma unroll
    for (int it = 0; it < 8; it++) {
      int jj = e0 + it*16;
      float twj = sTW[jj], tbj = sTB[jj];
      float w0 = 0.f, w1 = 0.f;
      #pragma unroll
      for (int k = 0; k < K; k++) {
        float c = cosr(__fadd_rn(__fmul_rn(dtr[k], twj), tbj));
        w0 += a0r[k]*c; w1 += a1r[k]*c;
      }
      sGWS[n*520 + 128 + jj] = cvtbf(w0);
      sGWS[n*520 + 384 + jj] = cvtbf(w1);
    }
  }
  __syncthreads();

  // G2: o = wsum_h @ Wv_h (+bv) -> sOP2 cols 0..255 (dead region)
  {
    int h = wv >> 1, ntb = (wv & 1)*4;
    bf16x8 a[8];
    #pragma unroll
    for (int kk = 0; kk < 8; kk++)
      a[kk] = ldb8(&sGWS[col*520 + h*256 + kk*32 + chunk*8]);
    f32x4 acc[4];
    #pragma unroll
    for (int t = 0; t < 4; t++) acc[t] = (f32x4){0.f,0.f,0.f,0.f};
    const ushort* BP = wsu + VPKo + (long)(l*2+h)*32768;
    #pragma unroll
    for (int t = 0; t < 4; t++) {
      int nt = ntb + t;
      #pragma unroll
      for (int kk = 0; kk < 8; kk++) {
        bf16x8 b = ldb8(&BP[((nt*8+kk)*64 + lane)*8]);
        acc[t] = __builtin_amdgcn_mfma_f32_16x16x32_bf16(a[kk], b, acc[t], 0, 0, 0);
      }
    }
    #pragma unroll
    for (int t = 0; t < 4; t++) {
      int ocol = h*128 + (ntb+t)*16 + col;
      float bb = bv[l*256 + ocol];
      #pragma unroll
      for (int r = 0; r < 4; r++)
        sOP2[(chunk*4+r)*392 + ocol] = cvtbf(acc[t][r] + bb);
    }
  }
  __syncthreads();

  // G3: oo = o @ Wo (+bo, anyv mask) -> sOP2 cols 0..255 (in-place via pre-load + barrier)
  {
    bf16x8 a[8];
    #pragma unroll
    for (int kk = 0; kk < 8; kk++)
      a[kk] = ldb8(&sOP2[col*392 + kk*32 + chunk*8]);
    __syncthreads();   // all o-frags read before oo overwrites
    f32x4 acc[4];
    #pragma unroll
    for (int t = 0; t < 4; t++) acc[t] = (f32x4){0.f,0.f,0.f,0.f};
    const ushort* BP = wsu + OPKo + (long)l*65536;
    #pragma unroll
    for (int t = 0; t < 4; t++) {
      int nt = wv*4 + t;
      #pragma unroll
      for (int kk = 0; kk < 8; kk++) {
        bf16x8 b = ldb8(&BP[((nt*8+kk)*64 + lane)*8]);
        acc[t] = __builtin_amdgcn_mfma_f32_16x16x32_bf16(a[kk], b, acc[t], 0, 0, 0);
      }
    }
    #pragma unroll
    for (int t = 0; t < 4; t++) {
      int e = (wv*4+t)*16 + col;
      float bb = bo[l*256 + e];
      #pragma unroll
      for (int r = 0; r < 4; r++) {
        int row = chunk*4 + r;
        float v = imem[64+row] ? (acc[t][r] + bb) : 0.f;
        sOP2[row*392 + e] = cvtbf(v);
      }
    }
  }
  __syncthreads();

  // G4: h1 = [oo,feat] @ W1 (+b1, relu) -> sOP2 cols 0..127
  {
    bf16x8 a[12];
    #pragma unroll
    for (int kk = 0; kk < 12; kk++)
      a[kk] = ldb8(&sOP2[col*392 + kk*32 + chunk*8]);
    __syncthreads();   // all oo/feat frags read before h1 overwrites
    f32x4 acc[2];
    acc[0] = (f32x4){0.f,0.f,0.f,0.f}; acc[1] = (f32x4){0.f,0.f,0.f,0.f};
    const ushort* BP = wsu + W1PKo + (long)l*49152;
    #pragma unroll
    for (int t = 0; t < 2; t++) {
      int nt = wv*2 + t;
      #pragma unroll
      for (int kk = 0; kk < 12; kk++) {
        bf16x8 b = ldb8(&BP[((nt*12+kk)*64 + lane)*8]);
        acc[t] = __builtin_amdgcn_mfma_f32_16x16x32_bf16(a[kk], b, acc[t], 0, 0, 0);
      }
    }
    #pragma unroll
    for (int t = 0; t < 2; t++) {
      int dcol = (wv*2+t)*16 + col;
      float bb = b1[l*128 + dcol];
      #pragma unroll
      for (int r = 0; r < 4; r++)
        sOP2[(chunk*4+r)*392 + dcol] = cvtbf(fmaxf(acc[t][r] + bb, 0.f));
    }
  }
  __syncthreads();

  // G5: out = h1 @ W2 (+b2) -> global f32
  {
    bf16x8 a[4];
    #pragma unroll
    for (int kk = 0; kk < 4; kk++)
      a[kk] = ldb8(&sOP2[col*392 + kk*32 + chunk*8]);
    f32x4 acc[2];
    acc[0] = (f32x4){0.f,0.f,0.f,0.f}; acc[1] = (f32x4){0.f,0.f,0.f,0.f};
    const ushort* BP = wsu + W2PKo + (long)l*16384;
    #pragma unroll
    for (int t = 0; t < 2; t++) {
      int nt = wv*2 + t;
      #pragma unroll
      for (int kk = 0; kk < 4; kk++) {
        bf16x8 b = ldb8(&BP[((nt*4+kk)*64 + lane)*8]);
        acc[t] = __builtin_amdgcn_mfma_f32_16x16x32_bf16(a[kk], b, acc[t], 0, 0, 0);
      }
    }
    #pragma unroll
    for (int t = 0; t < 2; t++) {
      int dcol = (wv*2+t)*16 + col;
      float bb = b2[l*128 + dcol];
      #pragma unroll
      for (int r = 0; r < 4; r++) {
        int row = chunk*4 + r;
        float v = acc[t][r] + bb;
        if (LAYER == 0) { if (imem[80+row]) wsf[OFF_NBR + (long)imem[48+row]*D + dcol] = v; }
        else            out[(long)(blk*G + row)*D + dcol] = v;
      }
    }
  }
}

extern "C" void kernel_launch(void* const* d_in, const int* in_sizes, int n_in,
                              void* d_out, int out_size, void* d_ws, size_t ws_size,
                              hipStream_t stream) {
  const int* nodes  = (const int*)d_in[0];
  const int* edges  = (const int*)d_in[1];
  const int* tst    = (const int*)d_in[2];
  const int* u_neig = (const int*)d_in[4];
  const int* u_edges= (const int*)d_in[5];
  const int* u_times= (const int*)d_in[6];
  const int* u_mask = (const int*)d_in[7];
  const int* i_neig = (const int*)d_in[8];
  const int* i_times= (const int*)d_in[10];
  const int* i_mask = (const int*)d_in[11];
  const float* user_emb = (const float*)d_in[12];
  const float* item_emb = (const float*)d_in[13];
  const float* time_w = (const float*)d_in[14];
  const float* time_b = (const float*)d_in[15];
  const float* Wq = (const float*)d_in[16]; const float* bq = (const float*)d_in[17];
  const float* Wk = (const float*)d_in[18]; const float* bk = (const float*)d_in[19];
  const float* Wv = (const float*)d_in[20]; const float* bv = (const float*)d_in[21];
  const float* Wo = (const float*)d_in[22]; const float* bo = (const float*)d_in[23];
  const float* W1 = (const float*)d_in[24]; const float* b1 = (const float*)d_in[25];
  const float* W2 = (const float*)d_in[26]; const float* b2 = (const float*)d_in[27];
  float* ws = (float*)d_ws;
  float* out = (float*)d_out;

  precompute2<<<dim3(516), dim3(256), 0, stream>>>(Wq, Wk, bq, bk, time_b, ws);
  packw<<<dim3(1536), dim3(256), 0, stream>>>(Wv, Wo, W1, W2, ws);
  compact_valid<<<dim3(160), dim3(256), 0, stream>>>(edges, u_mask, ws);

  attend<0><<<dim3(NSLOT/G), dim3(256), 0, stream>>>(
      nodes, edges, tst, u_edges, u_neig, u_times, u_mask,
      i_neig, i_times, i_mask, user_emb, item_emb, time_w, time_b,
      bv, bo, b1, b2, ws, out);

  attend<1><<<dim3(NB_B/G), dim3(256), 0, stream>>>(
      nodes, edges, tst, u_edges, u_neig, u_times, u_mask,
      i_neig, i_times, i_mask, user_emb, item_emb, time_w, time_b,
      bv, bo, b1, b2, ws, out);
}

// Round 10
// 166.786 us; speedup vs baseline: 1.4517x; 1.4391x over previous
//
#include <hip/hip_runtime.h>
#include <hip/hip_bf16.h>

#define TBL 50
#define K 20
#define D 128
#define E 256
#define NB_B 2048
#define NSLOT (NB_B*K)     // 40960
#define G 16

typedef unsigned short ushort;
typedef unsigned short ushort8 __attribute__((ext_vector_type(8)));
typedef float f32x4 __attribute__((ext_vector_type(4)));
typedef __bf16 bf16x8 __attribute__((ext_vector_type(8)));

// ws float offsets
#define OFF_GC    0              // [l2][512] f32
#define OFF_U     1024           // [l2*2][128] f32
#define OFF_CC    1536           // [4] f32
#define OFF_PKF   2052           // packed bf16 weights (524288 ushorts)
#define OFF_NBRB  264196         // NBR bf16 [40960][128] ushorts (2621440 floats)
#define OFF_CNT   2885636        // int count; int compact[40960]
#define OFF_UEB   2926600        // user_emb bf16 [100000][128] ushorts (6400000 floats)
#define WS_NEED_F (OFF_UEB + 6400000)
// ushort offsets inside PK region
#define APKo   0
#define VPKo   131072
#define OPKo   262144
#define W1PKo  393216
#define W2PKo  491520

__device__ __forceinline__ float cosr(float x) {
  const float HI = 0.15915493667125702f;   // fl(1/2pi)
  const float LO = 6.4206383e-9f;
  float k = rintf(x * HI);
  float f = __fmaf_rn(x, HI, -k);
  f = __fmaf_rn(x, LO, f);
  return __builtin_amdgcn_cosf(f);         // v_cos_f32 (revolutions)
}
__device__ __forceinline__ float b2f(ushort u) {
  return __uint_as_float(((unsigned)u) << 16);
}
__device__ __forceinline__ ushort cvtbf(float f) {
  unsigned u = __float_as_uint(f);
  return (ushort)((u + 0x7FFF + ((u >> 16) & 1)) >> 16);
}
__device__ __forceinline__ bf16x8 ldb8(const ushort* p) {
  union { ushort8 u; bf16x8 b; } c;
  c.u = *(const ushort8*)p;
  return c.b;
}

__global__ __launch_bounds__(256) void precompute2(
    const float* __restrict__ Wq, const float* __restrict__ Wk,
    const float* __restrict__ bq, const float* __restrict__ bk,
    const float* __restrict__ time_b, float* __restrict__ ws)
{
  __shared__ float sqc[128], ctb[128];
  int b = blockIdx.x, t = threadIdx.x;
  ushort* wsu = (ushort*)(ws + OFF_PKF);
  if (b < 512) {           // A[l][h][i][j] -> APK bf16
    int l = b >> 8, h = (b >> 7) & 1, i = b & 127;
    float s = 0.f;
    const float* wq = Wq + l*65536 + h*32768 + i;
    const float* wk = Wk + l*65536 + h*32768 + t;
    for (int m = 0; m < 128; m++) s += wq[m*256]*wk[m*256];
    int N = h*256 + t;
    int nt = N >> 4, cl = N & 15;
    int kk = i >> 5, ch = (i >> 3) & 3, bb = i & 7;
    wsu[APKo + (long)l*65536 + (((nt*4+kk)*64 + ch*16 + cl)*8) + bb] = cvtbf(s);
  } else {
    int q = b - 512, l = q >> 1, h = q & 1;
    if (t < 128) ctb[t] = cosf(time_b[t]);
    __syncthreads();
    if (t < 128) {
      int e = h*128 + t;
      float a = bq[l*256 + e];
      const float* wq = Wq + l*65536 + e*256 + 128;
      for (int m = 0; m < 128; m++) a += wq[m]*ctb[m];
      sqc[t] = a;
    }
    __syncthreads();
    { float s = 0.f;      // gc
      const float* wk = Wk + l*65536 + h*32768 + t;
      for (int m = 0; m < 128; m++) s += sqc[m]*wk[m*256];
      ws[OFF_GC + l*512 + h*256 + t] = s; }
    if (t < 128) {        // u
      float s = 0.f;
      const float* wq = Wq + l*65536 + h*32768 + t;
      const float* bkp = bk + l*256 + h*128;
      for (int m = 0; m < 128; m++) s += wq[m*256]*bkp[m];
      ws[OFF_U + (l*2+h)*128 + t] = s; }
    if (t == 254) {       // cc
      float s = 0.f;
      const float* bkp = bk + l*256 + h*128;
      for (int m = 0; m < 128; m++) s += sqc[m]*bkp[m];
      ws[OFF_CC + l*2+h] = s; }
  }
}

__global__ __launch_bounds__(256) void packw(
    const float* __restrict__ Wv, const float* __restrict__ Wo,
    const float* __restrict__ W1, const float* __restrict__ W2,
    float* __restrict__ ws)
{
  int idx = blockIdx.x*256 + threadIdx.x;   // < 393216
  ushort* wsu = (ushort*)(ws + OFF_PKF);
  if (idx == 0) *(int*)(ws + OFF_CNT) = 0;
  if (idx < 131072) {          // VPK
    int q = idx >> 15, r = idx & 32767, l = q >> 1, h = q & 1;
    int bb = r & 7, lane = (r >> 3) & 63, kk = (r >> 9) & 7, nt = r >> 12;
    int k = kk*32 + (lane>>4)*8 + bb, d = nt*16 + (lane&15);
    wsu[VPKo + idx] = cvtbf(Wv[l*65536 + (h*128+d)*256 + k]);
  } else if (idx < 262144) {   // OPK
    int rel = idx - 131072, l = rel >> 16, r = rel & 65535;
    int bb = r & 7, lane = (r >> 3) & 63, kk = (r >> 9) & 7, nt = r >> 12;
    int k = kk*32 + (lane>>4)*8 + bb, e = nt*16 + (lane&15);
    wsu[OPKo + rel] = cvtbf(Wo[l*65536 + e*256 + k]);
  } else if (idx < 360448) {   // W1PK
    int rel = idx - 262144, l = rel / 49152, r = rel % 49152;
    int nt = r / 6144, rr = r - nt*6144;
    int kk = rr >> 9, lane = (rr >> 3) & 63, bb = rr & 7;
    int k = kk*32 + (lane>>4)*8 + bb, d = nt*16 + (lane&15);
    wsu[W1PKo + rel] = cvtbf(W1[l*49152 + d*384 + k]);
  } else {                     // W2PK
    int rel = idx - 360448, l = rel >> 14, r = rel & 16383;
    int nt = r >> 11, rr = r & 2047;
    int kk = rr >> 9, lane = (rr >> 3) & 63, bb = rr & 7;
    int k = kk*32 + (lane>>4)*8 + bb, d = nt*16 + (lane&15);
    wsu[W2PKo + rel] = cvtbf(W2[l*16384 + d*128 + k]);
  }
}

__global__ __launch_bounds__(256) void pack_emb(
    const float* __restrict__ emb, float* __restrict__ ws)
{
  int idx = blockIdx.x*256 + threadIdx.x;   // < 1600000
  if (idx < 1600000) {
    float4 a = ((const float4*)emb)[idx*2];
    float4 b = ((const float4*)emb)[idx*2+1];
    ushort8 o;
    o[0]=cvtbf(a.x); o[1]=cvtbf(a.y); o[2]=cvtbf(a.z); o[3]=cvtbf(a.w);
    o[4]=cvtbf(b.x); o[5]=cvtbf(b.y); o[6]=cvtbf(b.z); o[7]=cvtbf(b.w);
    ((ushort8*)(ws + OFF_UEB))[idx] = o;
  }
}

__global__ __launch_bounds__(256) void compact_valid(
    const int* __restrict__ edges, const int* __restrict__ u_mask,
    float* __restrict__ ws)
{
  int idx = blockIdx.x*256 + threadIdx.x;    // < 40960
  int b = idx / K, s = idx - b*K;
  int pe = edges[b];
  if (u_mask[pe*TBL + (TBL-K) + s] > 0) {
    int pos = atomicAdd((int*)(ws + OFF_CNT), 1);
    ((int*)(ws + OFF_CNT))[1 + pos] = idx;
  }
}

template<int LAYER, bool NBF16>
__global__ __launch_bounds__(256, 3) void attend(
    const int* __restrict__ nodes, const int* __restrict__ edges, const int* __restrict__ tstamps,
    const int* __restrict__ u_edges, const int* __restrict__ u_neig,
    const int* __restrict__ u_times, const int* __restrict__ u_mask,
    const int* __restrict__ i_neig, const int* __restrict__ i_times, const int* __restrict__ i_mask,
    const float* __restrict__ user_emb, const float* __restrict__ item_emb,
    const float* __restrict__ time_w, const float* __restrict__ time_b,
    const float* __restrict__ bv, const float* __restrict__ bo,
    const float* __restrict__ b1, const float* __restrict__ b2,
    float* __restrict__ wsf, float* __restrict__ out)
{
  __shared__ __align__(16) ushort sOP2[16*392];  // [oo(256) | feat(128) | pad]
  __shared__ __align__(16) ushort sGWS[16*520];  // g then wsum
  __shared__ __align__(16) ushort sOP1[16*264];  // o then h1
  __shared__ float sTW[128], sTB[128], sAL[640], sQB[32];
  __shared__ int imem[96];
  __shared__ int nbm[960];

  const int tid = threadIdx.x, blk = blockIdx.x, l = LAYER;
  const int lane = tid & 63, wv = tid >> 6;
  const int col = lane & 15, chunk = lane >> 4;
  const ushort* wsu = (const ushort*)(wsf + OFF_PKF);
  // neighbor-feature sources
  const ushort* nbu = NBF16 ? ((LAYER == 0) ? (const ushort*)(wsf + OFF_UEB)
                                            : (const ushort*)(wsf + OFF_NBRB))
                            : (const ushort*)nullptr;
  const float*  nbf = user_emb;  // f32 fallback (LAYER==0 only)
  ushort* nbrOut = (ushort*)(wsf + OFF_NBRB);

  int count = (LAYER == 0) ? *(const int*)(wsf + OFF_CNT) : NB_B;
  if (blk*G >= count) return;

  if (tid < G) {
    int idx = blk*G + tid; int act = idx < count ? 1 : 0;
    int slot, nid, ntm, erow;
    if (LAYER == 0) {
      int ii = act ? idx : 0;
      slot = ((const int*)(wsf + OFF_CNT))[1 + ii];
      int bb = slot / K, s = slot - bb*K;
      int base = edges[bb]*TBL + (TBL-K) + s;
      nid = u_neig[base]; ntm = u_times[base]; erow = u_edges[base];
    } else { slot = idx; nid = nodes[idx]; ntm = tstamps[idx]; erow = edges[idx]; }
    imem[tid] = nid; imem[16+tid] = ntm; imem[32+tid] = erow;
    imem[48+tid] = slot; imem[80+tid] = act;
  }
  if (tid < 128) { sTW[tid] = time_w[tid]; sTB[tid] = time_b[tid]; }
  __syncthreads();

  // P0: gather feat -> OP2 cols 256..383 (bf16); neighbor meta
  const float* nemb = (LAYER == 0) ? item_emb : user_emb;
  #pragma unroll
  for (int it = 0; it < 8; it++) {
    int idx = tid + it*256, n = idx >> 7, i = idx & 127;
    sOP2[n*392 + 256 + i] = cvtbf(nemb[(long)imem[n]*D + i]);
  }
  #pragma unroll
  for (int it = 0; it < 2; it++) {
    int p = tid + it*256;
    if (p < G*K) {
      int n = p / K, k = p - n*K;
      int base = imem[32+n]*TBL + (TBL-K) + k;
      if (LAYER == 0) { nbm[p] = i_neig[base]; nbm[320+p] = i_times[base]; nbm[640+p] = i_mask[base]; }
      else            { nbm[p] = (blk*G+n)*K + k; nbm[320+p] = u_times[base]; nbm[640+p] = u_mask[base]; }
    }
  }
  __syncthreads();

  // G1: g[16x512] = feat[16x128] @ A (+gc) -> sGWS bf16
  {
    bf16x8 a[4];
    #pragma unroll
    for (int kk = 0; kk < 4; kk++)
      a[kk] = ldb8(&sOP2[col*392 + 256 + kk*32 + chunk*8]);
    f32x4 acc[8];
    #pragma unroll
    for (int t = 0; t < 8; t++) acc[t] = (f32x4){0.f,0.f,0.f,0.f};
    const ushort* BP = wsu + APKo + (long)l*65536;
    #pragma unroll
    for (int t = 0; t < 8; t++) {
      int nt = wv*8 + t;
      #pragma unroll
      for (int kk = 0; kk < 4; kk++) {
        bf16x8 b = ldb8(&BP[((nt*4+kk)*64 + lane)*8]);
        acc[t] = __builtin_amdgcn_mfma_f32_16x16x32_bf16(a[kk], b, acc[t], 0, 0, 0);
      }
    }
    #pragma unroll
    for (int t = 0; t < 8; t++) {
      int N = (wv*8+t)*16 + col;
      float gcv = wsf[OFF_GC + l*512 + N];
      #pragma unroll
      for (int r = 0; r < 4; r++)
        sGWS[(chunk*4+r)*520 + N] = cvtbf(acc[t][r] + gcv);
    }
  }
  if (tid < 32) {   // qb[n][h]
    int n = tid >> 1, h = tid & 1;
    float s = wsf[OFF_CC + l*2 + h];
    const float* u = wsf + OFF_U + (l*2+h)*128;
    for (int i = 0; i < 128; i++) s += b2f(sOP2[n*392 + 256 + i])*u[i];
    sQB[tid] = s;
  }
  __syncthreads();

  // Phase A: 320 scores, balanced 80/wave
  {
    auto scoreItem = [&](int p) {
      int n = p / K, k = p - n*K;
      float dtf = (float)(imem[16+n] - nbm[320+p]);
      const ushort8* gp = (const ushort8*)&sGWS[n*520];
      float a0 = 0.f, a1 = 0.f;
      if constexpr (NBF16) {
        const ushort8* fr8 = (const ushort8*)(nbu + (long)nbm[p]*D);
        #pragma unroll 4
        for (int c = 0; c < 16; c++) {
          ushort8 f = fr8[c];
          ushort8 g0 = gp[c], g1 = gp[32+c];
          float f0=b2f(f[0]),f1v=b2f(f[1]),f2=b2f(f[2]),f3=b2f(f[3]);
          float f4=b2f(f[4]),f5=b2f(f[5]),f6=b2f(f[6]),f7=b2f(f[7]);
          a0 += f0*b2f(g0[0]) + f1v*b2f(g0[1]) + f2*b2f(g0[2]) + f3*b2f(g0[3])
              + f4*b2f(g0[4]) + f5*b2f(g0[5]) + f6*b2f(g0[6]) + f7*b2f(g0[7]);
          a1 += f0*b2f(g1[0]) + f1v*b2f(g1[1]) + f2*b2f(g1[2]) + f3*b2f(g1[3])
              + f4*b2f(g1[4]) + f5*b2f(g1[5]) + f6*b2f(g1[6]) + f7*b2f(g1[7]);
        }
      } else {
        const float4* fr = (const float4*)(nbf + (long)nbm[p]*D);
        #pragma unroll 4
        for (int c = 0; c < 16; c++) {
          float4 f0 = fr[2*c], f1 = fr[2*c+1];
          ushort8 g0 = gp[c], g1 = gp[32+c];
          a0 += f0.x*b2f(g0[0]) + f0.y*b2f(g0[1]) + f0.z*b2f(g0[2]) + f0.w*b2f(g0[3])
              + f1.x*b2f(g0[4]) + f1.y*b2f(g0[5]) + f1.z*b2f(g0[6]) + f1.w*b2f(g0[7]);
          a1 += f0.x*b2f(g1[0]) + f0.y*b2f(g1[1]) + f0.z*b2f(g1[2]) + f0.w*b2f(g1[3])
              + f1.x*b2f(g1[4]) + f1.y*b2f(g1[5]) + f1.z*b2f(g1[6]) + f1.w*b2f(g1[7]);
        }
      }
      #pragma unroll 2
      for (int c = 0; c < 16; c++) {
        ushort8 g0 = gp[16+c], g1 = gp[48+c];
        float a0c = 0.f, a1c = 0.f;
        #pragma unroll
        for (int j = 0; j < 8; j++) {
          float cv = cosr(__fadd_rn(__fmul_rn(dtf, sTW[c*8+j]), sTB[c*8+j]));
          a0c += cv*b2f(g0[j]); a1c += cv*b2f(g1[j]);
        }
        a0 += a0c; a1 += a1c;
      }
      int m = nbm[640+p];
      const float invsq = 0.08838834764831845f;
      sAL[n*40 + k]      = m > 0 ? (a0 + sQB[n*2])*invsq   : -1e9f;
      sAL[n*40 + 20 + k] = m > 0 ? (a1 + sQB[n*2+1])*invsq : -1e9f;
    };
    scoreItem(wv*80 + lane);
    if (lane < 16) scoreItem(wv*80 + 64 + lane);
  }
  __syncthreads();

  // softmax
  if (tid < 2*G) {
    int n = tid >> 1, h = tid & 1;
    float* a = &sAL[n*40 + h*20];
    float mx = -1e30f;
    for (int k = 0; k < K; k++) mx = fmaxf(mx, a[k]);
    float s = 0.f;
    for (int k = 0; k < K; k++) { float e = __expf(a[k]-mx); a[k] = e; s += e; }
    float inv = 1.f/s;
    for (int k = 0; k < K; k++) a[k] *= inv;
    if (h == 0) { int any = 0;
      for (int k = 0; k < K; k++) any |= nbm[640 + n*20 + k];
      imem[64+n] = any; }
  }
  __syncthreads();

  // Phase C: wsum -> sGWS bf16 rows [n][h*256+j]
  {
    const int n = tid >> 4, e0 = tid & 15;
    float a0r[K], a1r[K], dtr[K]; int rowr[K];
    #pragma unroll
    for (int k = 0; k < K; k++) {
      a0r[k] = sAL[n*40 + k]; a1r[k] = sAL[n*40 + 20 + k];
      dtr[k] = (float)(imem[16+n] - nbm[320 + n*20 + k]);
      rowr[k] = nbm[n*20 + k];
    }
    #pragma unroll
    for (int it = 0; it < 8; it++) {
      int e = e0 + it*16;
      float w0 = 0.f, w1 = 0.f;
      #pragma unroll
      for (int k = 0; k < K; k++) {
        float f = NBF16 ? b2f(nbu[(long)rowr[k]*D + e]) : nbf[(long)rowr[k]*D + e];
        w0 += a0r[k]*f; w1 += a1r[k]*f;
      }
      sGWS[n*520 + e]       = cvtbf(w0);
      sGWS[n*520 + 256 + e] = cvtbf(w1);
    }
    #pragma unroll
    for (int it = 0; it < 8; it++) {
      int jj = e0 + it*16;
      float twj = sTW[jj], tbj = sTB[jj];
      float w0 = 0.f, w1 = 0.f;
      #pragma unroll
      for (int k = 0; k < K; k++) {
        float c = cosr(__fadd_rn(__fmul_rn(dtr[k], twj), tbj));
        w0 += a0r[k]*c; w1 += a1r[k]*c;
      }
      sGWS[n*520 + 128 + jj] = cvtbf(w0);
      sGWS[n*520 + 384 + jj] = cvtbf(w1);
    }
  }
  __syncthreads();

  // G2: o = wsum_h @ Wv_h (+bv) -> sOP1
  {
    int h = wv >> 1, ntb = (wv & 1)*4;
    bf16x8 a[8];
    #pragma unroll
    for (int kk = 0; kk < 8; kk++)
      a[kk] = ldb8(&sGWS[col*520 + h*256 + kk*32 + chunk*8]);
    f32x4 acc[4];
    #pragma unroll
    for (int t = 0; t < 4; t++) acc[t] = (f32x4){0.f,0.f,0.f,0.f};
    const ushort* BP = wsu + VPKo + (long)(l*2+h)*32768;
    #pragma unroll
    for (int t = 0; t < 4; t++) {
      int nt = ntb + t;
      #pragma unroll
      for (int kk = 0; kk < 8; kk++) {
        bf16x8 b = ldb8(&BP[((nt*8+kk)*64 + lane)*8]);
        acc[t] = __builtin_amdgcn_mfma_f32_16x16x32_bf16(a[kk], b, acc[t], 0, 0, 0);
      }
    }
    #pragma unroll
    for (int t = 0; t < 4; t++) {
      int ocol = h*128 + (ntb+t)*16 + col;
      float bb = bv[l*256 + ocol];
      #pragma unroll
      for (int r = 0; r < 4; r++)
        sOP1[(chunk*4+r)*264 + ocol] = cvtbf(acc[t][r] + bb);
    }
  }
  __syncthreads();

  // G3: oo = o @ Wo (+bo, anyv mask) -> sOP2 cols 0..255
  {
    bf16x8 a[8];
    #pragma unroll
    for (int kk = 0; kk < 8; kk++)
      a[kk] = ldb8(&sOP1[col*264 + kk*32 + chunk*8]);
    f32x4 acc[4];
    #pragma unroll
    for (int t = 0; t < 4; t++) acc[t] = (f32x4){0.f,0.f,0.f,0.f};
    const ushort* BP = wsu + OPKo + (long)l*65536;
    #pragma unroll
    for (int t = 0; t < 4; t++) {
      int nt = wv*4 + t;
      #pragma unroll
      for (int kk = 0; kk < 8; kk++) {
        bf16x8 b = ldb8(&BP[((nt*8+kk)*64 + lane)*8]);
        acc[t] = __builtin_amdgcn_mfma_f32_16x16x32_bf16(a[kk], b, acc[t], 0, 0, 0);
      }
    }
    #pragma unroll
    for (int t = 0; t < 4; t++) {
      int e = (wv*4+t)*16 + col;
      float bb = bo[l*256 + e];
      #pragma unroll
      for (int r = 0; r < 4; r++) {
        int row = chunk*4 + r;
        float v = imem[64+row] ? (acc[t][r] + bb) : 0.f;
        sOP2[row*392 + e] = cvtbf(v);
      }
    }
  }
  __syncthreads();

  // G4: h1 = [oo,feat] @ W1 (+b1, relu) -> sOP1 cols 0..127
  {
    bf16x8 a[12];
    #pragma unroll
    for (int kk = 0; kk < 12; kk++)
      a[kk] = ldb8(&sOP2[col*392 + kk*32 + chunk*8]);
    f32x4 acc[2];
    acc[0] = (f32x4){0.f,0.f,0.f,0.f}; acc[1] = (f32x4){0.f,0.f,0.f,0.f};
    const ushort* BP = wsu + W1PKo + (long)l*49152;
    #pragma unroll
    for (int t = 0; t < 2; t++) {
      int nt = wv*2 + t;
      #pragma unroll
      for (int kk = 0; kk < 12; kk++) {
        bf16x8 b = ldb8(&BP[((nt*12+kk)*64 + lane)*8]);
        acc[t] = __builtin_amdgcn_mfma_f32_16x16x32_bf16(a[kk], b, acc[t], 0, 0, 0);
      }
    }
    #pragma unroll
    for (int t = 0; t < 2; t++) {
      int dcol = (wv*2+t)*16 + col;
      float bb = b1[l*128 + dcol];
      #pragma unroll
      for (int r = 0; r < 4; r++)
        sOP1[(chunk*4+r)*264 + dcol] = cvtbf(fmaxf(acc[t][r] + bb, 0.f));
    }
  }
  __syncthreads();

  // G5: out = h1 @ W2 (+b2) -> NBR bf16 (L0) or global f32 (L1)
  {
    bf16x8 a[4];
    #pragma unroll
    for (int kk = 0; kk < 4; kk++)
      a[kk] = ldb8(&sOP1[col*264 + kk*32 + chunk*8]);
    f32x4 acc[2];
    acc[0] = (f32x4){0.f,0.f,0.f,0.f}; acc[1] = (f32x4){0.f,0.f,0.f,0.f};
    const ushort* BP = wsu + W2PKo + (long)l*16384;
    #pragma unroll
    for (int t = 0; t < 2; t++) {
      int nt = wv*2 + t;
      #pragma unroll
      for (int kk = 0; kk < 4; kk++) {
        bf16x8 b = ldb8(&BP[((nt*4+kk)*64 + lane)*8]);
        acc[t] = __builtin_amdgcn_mfma_f32_16x16x32_bf16(a[kk], b, acc[t], 0, 0, 0);
      }
    }
    #pragma unroll
    for (int t = 0; t < 2; t++) {
      int dcol = (wv*2+t)*16 + col;
      float bb = b2[l*128 + dcol];
      #pragma unroll
      for (int r = 0; r < 4; r++) {
        int row = chunk*4 + r;
        float v = acc[t][r] + bb;
        if (LAYER == 0) { if (imem[80+row]) nbrOut[(long)imem[48+row]*D + dcol] = cvtbf(v); }
        else            out[(long)(blk*G + row)*D + dcol] = v;
      }
    }
  }
}

extern "C" void kernel_launch(void* const* d_in, const int* in_sizes, int n_in,
                              void* d_out, int out_size, void* d_ws, size_t ws_size,
                              hipStream_t stream) {
  const int* nodes  = (const int*)d_in[0];
  const int* edges  = (const int*)d_in[1];
  const int* tst    = (const int*)d_in[2];
  const int* u_neig = (const int*)d_in[4];
  const int* u_edges= (const int*)d_in[5];
  const int* u_times= (const int*)d_in[6];
  const int* u_mask = (const int*)d_in[7];
  const int* i_neig = (const int*)d_in[8];
  const int* i_times= (const int*)d_in[10];
  const int* i_mask = (const int*)d_in[11];
  const float* user_emb = (const float*)d_in[12];
  const float* item_emb = (const float*)d_in[13];
  const float* time_w = (const float*)d_in[14];
  const float* time_b = (const float*)d_in[15];
  const float* Wq = (const float*)d_in[16]; const float* bq = (const float*)d_in[17];
  const float* Wk = (const float*)d_in[18]; const float* bk = (const float*)d_in[19];
  const float* Wv = (const float*)d_in[20]; const float* bv = (const float*)d_in[21];
  const float* Wo = (const float*)d_in[22]; const float* bo = (const float*)d_in[23];
  const float* W1 = (const float*)d_in[24]; const float* b1 = (const float*)d_in[25];
  const float* W2 = (const float*)d_in[26]; const float* b2 = (const float*)d_in[27];
  float* ws = (float*)d_ws;
  float* out = (float*)d_out;

  bool emb16 = ws_size >= (size_t)WS_NEED_F * 4;

  precompute2<<<dim3(516), dim3(256), 0, stream>>>(Wq, Wk, bq, bk, time_b, ws);
  packw<<<dim3(1536), dim3(256), 0, stream>>>(Wv, Wo, W1, W2, ws);
  if (emb16) pack_emb<<<dim3(6250), dim3(256), 0, stream>>>(user_emb, ws);
  compact_valid<<<dim3(160), dim3(256), 0, stream>>>(edges, u_mask, ws);

  if (emb16)
    attend<0,true><<<dim3(NSLOT/G), dim3(256), 0, stream>>>(
        nodes, edges, tst, u_edges, u_neig, u_times, u_mask,
        i_neig, i_times, i_mask, user_emb, item_emb, time_w, time_b,
        bv, bo, b1, b2, ws, out);
  else
    attend<0,false><<<dim3(NSLOT/G), dim3(256), 0, stream>>>(
        nodes, edges, tst, u_edges, u_neig, u_times, u_mask,
        i_neig, i_times, i_mask, user_emb, item_emb, time_w, time_b,
        bv, bo, b1, b2, ws, out);

  attend<1,true><<<dim3(NB_B/G), dim3(256), 0, stream>>>(
      nodes, edges, tst, u_edges, u_neig, u_times, u_mask,
      i_neig, i_times, i_mask, user_emb, item_emb, time_w, time_b,
      bv, bo, b1, b2, ws, out);
}

// Round 11
// 165.288 us; speedup vs baseline: 1.4649x; 1.0091x over previous
//
#include <hip/hip_runtime.h>
#include <hip/hip_bf16.h>

#define TBL 50
#define K 20
#define D 128
#define E 256
#define NB_B 2048
#define NSLOT (NB_B*K)     // 40960
#define G 16

typedef unsigned short ushort;
typedef unsigned short ushort8 __attribute__((ext_vector_type(8)));
typedef float f32x4 __attribute__((ext_vector_type(4)));
typedef __bf16 bf16x8 __attribute__((ext_vector_type(8)));

// ws float offsets
#define OFF_GC    0              // [l2][512] f32
#define OFF_U     1024           // [l2*2][128] f32
#define OFF_CC    1536           // [4] f32
#define OFF_PKF   2052           // packed bf16 weights (524288 ushorts)
#define OFF_NBRB  264196         // NBR bf16 [40960][128] ushorts
#define OFF_CNT   2885636        // int count; int compact[40960]
#define OFF_UEB   2926600        // user_emb bf16 [100000][128] ushorts
#define WS_NEED_F (OFF_UEB + 6400000)
// ushort offsets inside PK region
#define APKo   0
#define VPKo   131072
#define OPKo   262144
#define W1PKo  393216
#define W2PKo  491520

__device__ __forceinline__ float cosr(float x) {
  const float HI = 0.15915493667125702f;   // fl(1/2pi)
  const float LO = 6.4206383e-9f;
  float k = rintf(x * HI);
  float f = __fmaf_rn(x, HI, -k);
  f = __fmaf_rn(x, LO, f);
  return __builtin_amdgcn_cosf(f);         // v_cos_f32 (revolutions)
}
__device__ __forceinline__ float b2f(ushort u) {
  return __uint_as_float(((unsigned)u) << 16);
}
__device__ __forceinline__ ushort cvtbf(float f) {
  unsigned u = __float_as_uint(f);
  return (ushort)((u + 0x7FFF + ((u >> 16) & 1)) >> 16);
}
__device__ __forceinline__ bf16x8 ldb8(const ushort* p) {
  union { ushort8 u; bf16x8 b; } c;
  c.u = *(const ushort8*)p;
  return c.b;
}

__global__ __launch_bounds__(256) void precompute2(
    const float* __restrict__ Wq, const float* __restrict__ Wk,
    const float* __restrict__ bq, const float* __restrict__ bk,
    const float* __restrict__ time_b, float* __restrict__ ws)
{
  __shared__ float sqc[128], ctb[128];
  int b = blockIdx.x, t = threadIdx.x;
  ushort* wsu = (ushort*)(ws + OFF_PKF);
  if (b < 512) {           // A[l][h][i][j] -> APK bf16
    int l = b >> 8, h = (b >> 7) & 1, i = b & 127;
    float s = 0.f;
    const float* wq = Wq + l*65536 + h*32768 + i;
    const float* wk = Wk + l*65536 + h*32768 + t;
    for (int m = 0; m < 128; m++) s += wq[m*256]*wk[m*256];
    int N = h*256 + t;
    int nt = N >> 4, cl = N & 15;
    int kk = i >> 5, ch = (i >> 3) & 3, bb = i & 7;
    wsu[APKo + (long)l*65536 + (((nt*4+kk)*64 + ch*16 + cl)*8) + bb] = cvtbf(s);
  } else {
    int q = b - 512, l = q >> 1, h = q & 1;
    if (t < 128) ctb[t] = cosf(time_b[t]);
    __syncthreads();
    if (t < 128) {
      int e = h*128 + t;
      float a = bq[l*256 + e];
      const float* wq = Wq + l*65536 + e*256 + 128;
      for (int m = 0; m < 128; m++) a += wq[m]*ctb[m];
      sqc[t] = a;
    }
    __syncthreads();
    { float s = 0.f;      // gc
      const float* wk = Wk + l*65536 + h*32768 + t;
      for (int m = 0; m < 128; m++) s += sqc[m]*wk[m*256];
      ws[OFF_GC + l*512 + h*256 + t] = s; }
    if (t < 128) {        // u
      float s = 0.f;
      const float* wq = Wq + l*65536 + h*32768 + t;
      const float* bkp = bk + l*256 + h*128;
      for (int m = 0; m < 128; m++) s += wq[m*256]*bkp[m];
      ws[OFF_U + (l*2+h)*128 + t] = s; }
    if (t == 254) {       // cc
      float s = 0.f;
      const float* bkp = bk + l*256 + h*128;
      for (int m = 0; m < 128; m++) s += sqc[m]*bkp[m];
      ws[OFF_CC + l*2+h] = s; }
  }
}

__global__ __launch_bounds__(256) void packw(
    const float* __restrict__ Wv, const float* __restrict__ Wo,
    const float* __restrict__ W1, const float* __restrict__ W2,
    float* __restrict__ ws)
{
  int idx = blockIdx.x*256 + threadIdx.x;   // < 393216
  ushort* wsu = (ushort*)(ws + OFF_PKF);
  if (idx == 0) *(int*)(ws + OFF_CNT) = 0;
  if (idx < 131072) {          // VPK
    int q = idx >> 15, r = idx & 32767, l = q >> 1, h = q & 1;
    int bb = r & 7, lane = (r >> 3) & 63, kk = (r >> 9) & 7, nt = r >> 12;
    int k = kk*32 + (lane>>4)*8 + bb, d = nt*16 + (lane&15);
    wsu[VPKo + idx] = cvtbf(Wv[l*65536 + (h*128+d)*256 + k]);
  } else if (idx < 262144) {   // OPK
    int rel = idx - 131072, l = rel >> 16, r = rel & 65535;
    int bb = r & 7, lane = (r >> 3) & 63, kk = (r >> 9) & 7, nt = r >> 12;
    int k = kk*32 + (lane>>4)*8 + bb, e = nt*16 + (lane&15);
    wsu[OPKo + rel] = cvtbf(Wo[l*65536 + e*256 + k]);
  } else if (idx < 360448) {   // W1PK
    int rel = idx - 262144, l = rel / 49152, r = rel % 49152;
    int nt = r / 6144, rr = r - nt*6144;
    int kk = rr >> 9, lane = (rr >> 3) & 63, bb = rr & 7;
    int k = kk*32 + (lane>>4)*8 + bb, d = nt*16 + (lane&15);
    wsu[W1PKo + rel] = cvtbf(W1[l*49152 + d*384 + k]);
  } else {                     // W2PK
    int rel = idx - 360448, l = rel >> 14, r = rel & 16383;
    int nt = r >> 11, rr = r & 2047;
    int kk = rr >> 9, lane = (rr >> 3) & 63, bb = rr & 7;
    int k = kk*32 + (lane>>4)*8 + bb, d = nt*16 + (lane&15);
    wsu[W2PKo + rel] = cvtbf(W2[l*16384 + d*128 + k]);
  }
}

__global__ __launch_bounds__(256) void pack_emb(
    const float* __restrict__ emb, float* __restrict__ ws)
{
  int idx = blockIdx.x*256 + threadIdx.x;   // < 1600000
  if (idx < 1600000) {
    float4 a = ((const float4*)emb)[idx*2];
    float4 b = ((const float4*)emb)[idx*2+1];
    ushort8 o;
    o[0]=cvtbf(a.x); o[1]=cvtbf(a.y); o[2]=cvtbf(a.z); o[3]=cvtbf(a.w);
    o[4]=cvtbf(b.x); o[5]=cvtbf(b.y); o[6]=cvtbf(b.z); o[7]=cvtbf(b.w);
    ((ushort8*)(ws + OFF_UEB))[idx] = o;
  }
}

__global__ __launch_bounds__(256) void compact_valid(
    const int* __restrict__ edges, const int* __restrict__ u_mask,
    float* __restrict__ ws)
{
  int idx = blockIdx.x*256 + threadIdx.x;    // < 40960
  int b = idx / K, s = idx - b*K;
  int pe = edges[b];
  if (u_mask[pe*TBL + (TBL-K) + s] > 0) {
    int pos = atomicAdd((int*)(ws + OFF_CNT), 1);
    ((int*)(ws + OFF_CNT))[1 + pos] = idx;
  }
}

template<int LAYER, bool NBF16>
__global__ __launch_bounds__(256, 3) void attend(
    const int* __restrict__ nodes, const int* __restrict__ edges, const int* __restrict__ tstamps,
    const int* __restrict__ u_edges, const int* __restrict__ u_neig,
    const int* __restrict__ u_times, const int* __restrict__ u_mask,
    const int* __restrict__ i_neig, const int* __restrict__ i_times, const int* __restrict__ i_mask,
    const float* __restrict__ user_emb, const float* __restrict__ item_emb,
    const float* __restrict__ time_w, const float* __restrict__ time_b,
    const float* __restrict__ bv, const float* __restrict__ bo,
    const float* __restrict__ b1, const float* __restrict__ b2,
    float* __restrict__ wsf, float* __restrict__ out)
{
  __shared__ __align__(16) ushort sOP2[16*392];  // [oo(256) | feat(128) | pad]
  __shared__ __align__(16) ushort sGWS[16*520];  // g then wsum
  __shared__ __align__(16) ushort sOP1[16*264];  // o then h1
  __shared__ float sTW[128], sTB[128], sAL[640], sQB[32];
  __shared__ int imem[96];
  __shared__ int nbm[960];

  const int tid = threadIdx.x, blk = blockIdx.x, l = LAYER;
  const int lane = tid & 63, wv = tid >> 6;
  const int col = lane & 15, chunk = lane >> 4;
  const ushort* wsu = (const ushort*)(wsf + OFF_PKF);
  const ushort* nbu = NBF16 ? ((LAYER == 0) ? (const ushort*)(wsf + OFF_UEB)
                                            : (const ushort*)(wsf + OFF_NBRB))
                            : (const ushort*)nullptr;
  const float*  nbf = user_emb;  // f32 fallback (LAYER==0 only)
  ushort* nbrOut = (ushort*)(wsf + OFF_NBRB);

  int count = (LAYER == 0) ? *(const int*)(wsf + OFF_CNT) : NB_B;
  if (blk*G >= count) return;

  if (tid < G) {
    int idx = blk*G + tid; int act = idx < count ? 1 : 0;
    int slot, nid, ntm, erow;
    if (LAYER == 0) {
      int ii = act ? idx : 0;
      slot = ((const int*)(wsf + OFF_CNT))[1 + ii];
      int bb = slot / K, s = slot - bb*K;
      int base = edges[bb]*TBL + (TBL-K) + s;
      nid = u_neig[base]; ntm = u_times[base]; erow = u_edges[base];
    } else { slot = idx; nid = nodes[idx]; ntm = tstamps[idx]; erow = edges[idx]; }
    imem[tid] = nid; imem[16+tid] = ntm; imem[32+tid] = erow;
    imem[48+tid] = slot; imem[80+tid] = act;
  }
  if (tid < 128) { sTW[tid] = time_w[tid]; sTB[tid] = time_b[tid]; }
  __syncthreads();

  // P0: gather feat -> OP2 cols 256..383 (bf16); neighbor meta
  const float* nemb = (LAYER == 0) ? item_emb : user_emb;
  #pragma unroll
  for (int it = 0; it < 8; it++) {
    int idx = tid + it*256, n = idx >> 7, i = idx & 127;
    sOP2[n*392 + 256 + i] = cvtbf(nemb[(long)imem[n]*D + i]);
  }
  #pragma unroll
  for (int it = 0; it < 2; it++) {
    int p = tid + it*256;
    if (p < G*K) {
      int n = p / K, k = p - n*K;
      int base = imem[32+n]*TBL + (TBL-K) + k;
      if (LAYER == 0) { nbm[p] = i_neig[base]; nbm[320+p] = i_times[base]; nbm[640+p] = i_mask[base]; }
      else            { nbm[p] = (blk*G+n)*K + k; nbm[320+p] = u_times[base]; nbm[640+p] = u_mask[base]; }
    }
  }
  __syncthreads();

  // G1: g[16x512] = feat[16x128] @ A (+gc) -> sGWS bf16
  {
    bf16x8 a[4];
    #pragma unroll
    for (int kk = 0; kk < 4; kk++)
      a[kk] = ldb8(&sOP2[col*392 + 256 + kk*32 + chunk*8]);
    f32x4 acc[8];
    #pragma unroll
    for (int t = 0; t < 8; t++) acc[t] = (f32x4){0.f,0.f,0.f,0.f};
    const ushort* BP = wsu + APKo + (long)l*65536;
    #pragma unroll
    for (int t = 0; t < 8; t++) {
      int nt = wv*8 + t;
      #pragma unroll
      for (int kk = 0; kk < 4; kk++) {
        bf16x8 b = ldb8(&BP[((nt*4+kk)*64 + lane)*8]);
        acc[t] = __builtin_amdgcn_mfma_f32_16x16x32_bf16(a[kk], b, acc[t], 0, 0, 0);
      }
    }
    #pragma unroll
    for (int t = 0; t < 8; t++) {
      int N = (wv*8+t)*16 + col;
      float gcv = wsf[OFF_GC + l*512 + N];
      #pragma unroll
      for (int r = 0; r < 4; r++)
        sGWS[(chunk*4+r)*520 + N] = cvtbf(acc[t][r] + gcv);
    }
  }
  if (tid < 32) {   // qb[n][h]
    int n = tid >> 1, h = tid & 1;
    float s = wsf[OFF_CC + l*2 + h];
    const float* u = wsf + OFF_U + (l*2+h)*128;
    for (int i = 0; i < 128; i++) s += b2f(sOP2[n*392 + 256 + i])*u[i];
    sQB[tid] = s;
  }
  __syncthreads();

  // Phase A: 320 scores, balanced 80/wave; feat loads clustered in 2 batches of 8
  {
    auto scoreItem = [&](int p) {
      int n = p / K, k = p - n*K;
      float dtf = (float)(imem[16+n] - nbm[320+p]);
      const ushort8* gp = (const ushort8*)&sGWS[n*520];
      float a0 = 0.f, a1 = 0.f;
      if constexpr (NBF16) {
        const ushort8* fr8 = (const ushort8*)(nbu + (long)nbm[p]*D);
        #pragma unroll
        for (int half = 0; half < 2; half++) {
          ushort8 f[8];
          #pragma unroll
          for (int c = 0; c < 8; c++) f[c] = fr8[half*8 + c];
          #pragma unroll
          for (int c = 0; c < 8; c++) {
            ushort8 g0 = gp[half*8 + c], g1 = gp[32 + half*8 + c];
            float f0=b2f(f[c][0]),f1v=b2f(f[c][1]),f2=b2f(f[c][2]),f3=b2f(f[c][3]);
            float f4=b2f(f[c][4]),f5=b2f(f[c][5]),f6=b2f(f[c][6]),f7=b2f(f[c][7]);
            a0 += f0*b2f(g0[0]) + f1v*b2f(g0[1]) + f2*b2f(g0[2]) + f3*b2f(g0[3])
                + f4*b2f(g0[4]) + f5*b2f(g0[5]) + f6*b2f(g0[6]) + f7*b2f(g0[7]);
            a1 += f0*b2f(g1[0]) + f1v*b2f(g1[1]) + f2*b2f(g1[2]) + f3*b2f(g1[3])
                + f4*b2f(g1[4]) + f5*b2f(g1[5]) + f6*b2f(g1[6]) + f7*b2f(g1[7]);
          }
        }
      } else {
        const float4* fr = (const float4*)(nbf + (long)nbm[p]*D);
        #pragma unroll 4
        for (int c = 0; c < 16; c++) {
          float4 f0 = fr[2*c], f1 = fr[2*c+1];
          ushort8 g0 = gp[c], g1 = gp[32+c];
          a0 += f0.x*b2f(g0[0]) + f0.y*b2f(g0[1]) + f0.z*b2f(g0[2]) + f0.w*b2f(g0[3])
              + f1.x*b2f(g0[4]) + f1.y*b2f(g0[5]) + f1.z*b2f(g0[6]) + f1.w*b2f(g0[7]);
          a1 += f0.x*b2f(g1[0]) + f0.y*b2f(g1[1]) + f0.z*b2f(g1[2]) + f0.w*b2f(g1[3])
              + f1.x*b2f(g1[4]) + f1.y*b2f(g1[5]) + f1.z*b2f(g1[6]) + f1.w*b2f(g1[7]);
        }
      }
      #pragma unroll 2
      for (int c = 0; c < 16; c++) {
        ushort8 g0 = gp[16+c], g1 = gp[48+c];
        float a0c = 0.f, a1c = 0.f;
        #pragma unroll
        for (int j = 0; j < 8; j++) {
          float cv = cosr(__fadd_rn(__fmul_rn(dtf, sTW[c*8+j]), sTB[c*8+j]));
          a0c += cv*b2f(g0[j]); a1c += cv*b2f(g1[j]);
        }
        a0 += a0c; a1 += a1c;
      }
      int m = nbm[640+p];
      const float invsq = 0.08838834764831845f;
      sAL[n*40 + k]      = m > 0 ? (a0 + sQB[n*2])*invsq   : -1e9f;
      sAL[n*40 + 20 + k] = m > 0 ? (a1 + sQB[n*2+1])*invsq : -1e9f;
    };
    scoreItem(wv*80 + lane);
    if (lane < 16) scoreItem(wv*80 + 64 + lane);
  }
  __syncthreads();

  // softmax
  if (tid < 2*G) {
    int n = tid >> 1, h = tid & 1;
    float* a = &sAL[n*40 + h*20];
    float mx = -1e30f;
    for (int k = 0; k < K; k++) mx = fmaxf(mx, a[k]);
    float s = 0.f;
    for (int k = 0; k < K; k++) { float e = __expf(a[k]-mx); a[k] = e; s += e; }
    float inv = 1.f/s;
    for (int k = 0; k < K; k++) a[k] *= inv;
    if (h == 0) { int any = 0;
      for (int k = 0; k < K; k++) any |= nbm[640 + n*20 + k];
      imem[64+n] = any; }
  }
  __syncthreads();

  // Phase C: wsum -> sGWS; thread owns 8 contiguous cols; k-major vector gathers
  {
    const int n = tid >> 4, e0 = tid & 15;
    float w0[8], w1[8];
    // feat part
    #pragma unroll
    for (int i = 0; i < 8; i++) { w0[i] = 0.f; w1[i] = 0.f; }
    #pragma unroll 4
    for (int k = 0; k < K; k++) {
      float a0k = sAL[n*40 + k], a1k = sAL[n*40 + 20 + k];
      if constexpr (NBF16) {
        ushort8 f = *(const ushort8*)(nbu + (long)nbm[n*20+k]*D + e0*8);
        #pragma unroll
        for (int i = 0; i < 8; i++) {
          float fi = b2f(f[i]);
          w0[i] += a0k*fi; w1[i] += a1k*fi;
        }
      } else {
        const float* fr = nbf + (long)nbm[n*20+k]*D + e0*8;
        float4 fa = *(const float4*)fr, fb = *(const float4*)(fr+4);
        w0[0]+=a0k*fa.x; w1[0]+=a1k*fa.x; w0[1]+=a0k*fa.y; w1[1]+=a1k*fa.y;
        w0[2]+=a0k*fa.z; w1[2]+=a1k*fa.z; w0[3]+=a0k*fa.w; w1[3]+=a1k*fa.w;
        w0[4]+=a0k*fb.x; w1[4]+=a1k*fb.x; w0[5]+=a0k*fb.y; w1[5]+=a1k*fb.y;
        w0[6]+=a0k*fb.z; w1[6]+=a1k*fb.z; w0[7]+=a0k*fb.w; w1[7]+=a1k*fb.w;
      }
    }
    #pragma unroll
    for (int i = 0; i < 8; i++) {
      sGWS[n*520 + e0*8 + i]       = cvtbf(w0[i]);
      sGWS[n*520 + 256 + e0*8 + i] = cvtbf(w1[i]);
    }
    // time part
    #pragma unroll
    for (int i = 0; i < 8; i++) { w0[i] = 0.f; w1[i] = 0.f; }
    float twv[8], tbv[8];
    #pragma unroll
    for (int i = 0; i < 8; i++) { twv[i] = sTW[e0*8+i]; tbv[i] = sTB[e0*8+i]; }
    for (int k = 0; k < K; k++) {
      float a0k = sAL[n*40 + k], a1k = sAL[n*40 + 20 + k];
      float dtf = (float)(imem[16+n] - nbm[320 + n*20 + k]);
      #pragma unroll
      for (int i = 0; i < 8; i++) {
        float c = cosr(__fadd_rn(__fmul_rn(dtf, twv[i]), tbv[i]));
        w0[i] += a0k*c; w1[i] += a1k*c;
      }
    }
    #pragma unroll
    for (int i = 0; i < 8; i++) {
      sGWS[n*520 + 128 + e0*8 + i] = cvtbf(w0[i]);
      sGWS[n*520 + 384 + e0*8 + i] = cvtbf(w1[i]);
    }
  }
  __syncthreads();

  // G2: o = wsum_h @ Wv_h (+bv) -> sOP1
  {
    int h = wv >> 1, ntb = (wv & 1)*4;
    bf16x8 a[8];
    #pragma unroll
    for (int kk = 0; kk < 8; kk++)
      a[kk] = ldb8(&sGWS[col*520 + h*256 + kk*32 + chunk*8]);
    f32x4 acc[4];
    #pragma unroll
    for (int t = 0; t < 4; t++) acc[t] = (f32x4){0.f,0.f,0.f,0.f};
    const ushort* BP = wsu + VPKo + (long)(l*2+h)*32768;
    #pragma unroll
    for (int t = 0; t < 4; t++) {
      int nt = ntb + t;
      #pragma unroll
      for (int kk = 0; kk < 8; kk++) {
        bf16x8 b = ldb8(&BP[((nt*8+kk)*64 + lane)*8]);
        acc[t] = __builtin_amdgcn_mfma_f32_16x16x32_bf16(a[kk], b, acc[t], 0, 0, 0);
      }
    }
    #pragma unroll
    for (int t = 0; t < 4; t++) {
      int ocol = h*128 + (ntb+t)*16 + col;
      float bb = bv[l*256 + ocol];
      #pragma unroll
      for (int r = 0; r < 4; r++)
        sOP1[(chunk*4+r)*264 + ocol] = cvtbf(acc[t][r] + bb);
    }
  }
  __syncthreads();

  // G3: oo = o @ Wo (+bo, anyv mask) -> sOP2 cols 0..255
  {
    bf16x8 a[8];
    #pragma unroll
    for (int kk = 0; kk < 8; kk++)
      a[kk] = ldb8(&sOP1[col*264 + kk*32 + chunk*8]);
    f32x4 acc[4];
    #pragma unroll
    for (int t = 0; t < 4; t++) acc[t] = (f32x4){0.f,0.f,0.f,0.f};
    const ushort* BP = wsu + OPKo + (long)l*65536;
    #pragma unroll
    for (int t = 0; t < 4; t++) {
      int nt = wv*4 + t;
      #pragma unroll
      for (int kk = 0; kk < 8; kk++) {
        bf16x8 b = ldb8(&BP[((nt*8+kk)*64 + lane)*8]);
        acc[t] = __builtin_amdgcn_mfma_f32_16x16x32_bf16(a[kk], b, acc[t], 0, 0, 0);
      }
    }
    #pragma unroll
    for (int t = 0; t < 4; t++) {
      int e = (wv*4+t)*16 + col;
      float bb = bo[l*256 + e];
      #pragma unroll
      for (int r = 0; r < 4; r++) {
        int row = chunk*4 + r;
        float v = imem[64+row] ? (acc[t][r] + bb) : 0.f;
        sOP2[row*392 + e] = cvtbf(v);
      }
    }
  }
  __syncthreads();

  // G4: h1 = [oo,feat] @ W1 (+b1, relu) -> sOP1 cols 0..127
  {
    bf16x8 a[12];
    #pragma unroll
    for (int kk = 0; kk < 12; kk++)
      a[kk] = ldb8(&sOP2[col*392 + kk*32 + chunk*8]);
    f32x4 acc[2];
    acc[0] = (f32x4){0.f,0.f,0.f,0.f}; acc[1] = (f32x4){0.f,0.f,0.f,0.f};
    const ushort* BP = wsu + W1PKo + (long)l*49152;
    #pragma unroll
    for (int t = 0; t < 2; t++) {
      int nt = wv*2 + t;
      #pragma unroll
      for (int kk = 0; kk < 12; kk++) {
        bf16x8 b = ldb8(&BP[((nt*12+kk)*64 + lane)*8]);
        acc[t] = __builtin_amdgcn_mfma_f32_16x16x32_bf16(a[kk], b, acc[t], 0, 0, 0);
      }
    }
    #pragma unroll
    for (int t = 0; t < 2; t++) {
      int dcol = (wv*2+t)*16 + col;
      float bb = b1[l*128 + dcol];
      #pragma unroll
      for (int r = 0; r < 4; r++)
        sOP1[(chunk*4+r)*264 + dcol] = cvtbf(fmaxf(acc[t][r] + bb, 0.f));
    }
  }
  __syncthreads();

  // G5: out = h1 @ W2 (+b2) -> NBR bf16 (L0) or global f32 (L1)
  {
    bf16x8 a[4];
    #pragma unroll
    for (int kk = 0; kk < 4; kk++)
      a[kk] = ldb8(&sOP1[col*264 + kk*32 + chunk*8]);
    f32x4 acc[2];
    acc[0] = (f32x4){0.f,0.f,0.f,0.f}; acc[1] = (f32x4){0.f,0.f,0.f,0.f};
    const ushort* BP = wsu + W2PKo + (long)l*16384;
    #pragma unroll
    for (int t = 0; t < 2; t++) {
      int nt = wv*2 + t;
      #pragma unroll
      for (int kk = 0; kk < 4; kk++) {
        bf16x8 b = ldb8(&BP[((nt*4+kk)*64 + lane)*8]);
        acc[t] = __builtin_amdgcn_mfma_f32_16x16x32_bf16(a[kk], b, acc[t], 0, 0, 0);
      }
    }
    #pragma unroll
    for (int t = 0; t < 2; t++) {
      int dcol = (wv*2+t)*16 + col;
      float bb = b2[l*128 + dcol];
      #pragma unroll
      for (int r = 0; r < 4; r++) {
        int row = chunk*4 + r;
        float v = acc[t][r] + bb;
        if (LAYER == 0) { if (imem[80+row]) nbrOut[(long)imem[48+row]*D + dcol] = cvtbf(v); }
        else            out[(long)(blk*G + row)*D + dcol] = v;
      }
    }
  }
}

extern "C" void kernel_launch(void* const* d_in, const int* in_sizes, int n_in,
                              void* d_out, int out_size, void* d_ws, size_t ws_size,
                              hipStream_t stream) {
  const int* nodes  = (const int*)d_in[0];
  const int* edges  = (const int*)d_in[1];
  const int* tst    = (const int*)d_in[2];
  const int* u_neig = (const int*)d_in[4];
  const int* u_edges= (const int*)d_in[5];
  const int* u_times= (const int*)d_in[6];
  const int* u_mask = (const int*)d_in[7];
  const int* i_neig = (const int*)d_in[8];
  const int* i_times= (const int*)d_in[10];
  const int* i_mask = (const int*)d_in[11];
  const float* user_emb = (const float*)d_in[12];
  const float* item_emb = (const float*)d_in[13];
  const float* time_w = (const float*)d_in[14];
  const float* time_b = (const float*)d_in[15];
  const float* Wq = (const float*)d_in[16]; const float* bq = (const float*)d_in[17];
  const float* Wk = (const float*)d_in[18]; const float* bk = (const float*)d_in[19];
  const float* Wv = (const float*)d_in[20]; const float* bv = (const float*)d_in[21];
  const float* Wo = (const float*)d_in[22]; const float* bo = (const float*)d_in[23];
  const float* W1 = (const float*)d_in[24]; const float* b1 = (const float*)d_in[25];
  const float* W2 = (const float*)d_in[26]; const float* b2 = (const float*)d_in[27];
  float* ws = (float*)d_ws;
  float* out = (float*)d_out;

  bool emb16 = ws_size >= (size_t)WS_NEED_F * 4;

  precompute2<<<dim3(516), dim3(256), 0, stream>>>(Wq, Wk, bq, bk, time_b, ws);
  packw<<<dim3(1536), dim3(256), 0, stream>>>(Wv, Wo, W1, W2, ws);
  if (emb16) pack_emb<<<dim3(6250), dim3(256), 0, stream>>>(user_emb, ws);
  compact_valid<<<dim3(160), dim3(256), 0, stream>>>(edges, u_mask, ws);

  if (emb16)
    attend<0,true><<<dim3(NSLOT/G), dim3(256), 0, stream>>>(
        nodes, edges, tst, u_edges, u_neig, u_times, u_mask,
        i_neig, i_times, i_mask, user_emb, item_emb, time_w, time_b,
        bv, bo, b1, b2, ws, out);
  else
    attend<0,false><<<dim3(NSLOT/G), dim3(256), 0, stream>>>(
        nodes, edges, tst, u_edges, u_neig, u_times, u_mask,
        i_neig, i_times, i_mask, user_emb, item_emb, time_w, time_b,
        bv, bo, b1, b2, ws, out);

  attend<1,true><<<dim3(NB_B/G), dim3(256), 0, stream>>>(
      nodes, edges, tst, u_edges, u_neig, u_times, u_mask,
      i_neig, i_times, i_mask, user_emb, item_emb, time_w, time_b,
      bv, bo, b1, b2, ws, out);
}

// Round 12
// 143.296 us; speedup vs baseline: 1.6897x; 1.1535x over previous
//
#include <hip/hip_runtime.h>
#include <hip/hip_bf16.h>
#include <hip/hip_fp16.h>

#define TBL 50
#define K 20
#define D 128
#define E 256
#define NB_B 2048
#define NSLOT (NB_B*K)     // 40960
#define G 16

typedef unsigned short ushort;
typedef unsigned short ushort8 __attribute__((ext_vector_type(8)));
typedef float f32x4 __attribute__((ext_vector_type(4)));
typedef _Float16 half8 __attribute__((ext_vector_type(8)));

// ws float offsets
#define OFF_GC    0              // [l2][512] f32
#define OFF_U     1024           // [l2*2][128] f32
#define OFF_CC    1536           // [4] f32
#define OFF_PKF   2052           // packed f16 weights (524288 ushorts)
#define OFF_NBRB  264196         // NBR f16 [40960][128] ushorts
#define OFF_CNT   2885636        // int count; int compact[40960]
#define OFF_UEB   2926600        // user_emb f16 [100000][128] ushorts
#define WS_NEED_F (OFF_UEB + 6400000)
// ushort offsets inside PK region
#define APKo   0
#define VPKo   131072
#define OPKo   262144
#define W1PKo  393216
#define W2PKo  491520

__device__ __forceinline__ float cosr(float x) {
  const float HI = 0.15915493667125702f;   // fl(1/2pi)
  const float LO = 6.4206383e-9f;
  float k = rintf(x * HI);
  float f = __fmaf_rn(x, HI, -k);
  f = __fmaf_rn(x, LO, f);
  return __builtin_amdgcn_cosf(f);         // v_cos_f32 (revolutions)
}
__device__ __forceinline__ ushort cvth(float f) {
  union { _Float16 h; ushort u; } c; c.h = (_Float16)f; return c.u;
}
__device__ __forceinline__ float h2f(ushort u) {
  union { ushort u; _Float16 h; } c; c.u = u; return (float)c.h;
}
__device__ __forceinline__ half8 ldh8(const ushort* p) {
  union { ushort8 u; half8 h; } c;
  c.u = *(const ushort8*)p;
  return c.h;
}

__global__ __launch_bounds__(256) void precompute2(
    const float* __restrict__ Wq, const float* __restrict__ Wk,
    const float* __restrict__ bq, const float* __restrict__ bk,
    const float* __restrict__ time_b, float* __restrict__ ws)
{
  __shared__ float sqc[128], ctb[128];
  int b = blockIdx.x, t = threadIdx.x;
  ushort* wsu = (ushort*)(ws + OFF_PKF);
  if (b < 512) {           // A[l][h][i][j] -> APK f16
    int l = b >> 8, h = (b >> 7) & 1, i = b & 127;
    float s = 0.f;
    const float* wq = Wq + l*65536 + h*32768 + i;
    const float* wk = Wk + l*65536 + h*32768 + t;
    for (int m = 0; m < 128; m++) s += wq[m*256]*wk[m*256];
    int N = h*256 + t;
    int nt = N >> 4, cl = N & 15;
    int kk = i >> 5, ch = (i >> 3) & 3, bb = i & 7;
    wsu[APKo + (long)l*65536 + (((nt*4+kk)*64 + ch*16 + cl)*8) + bb] = cvth(s);
  } else {
    int q = b - 512, l = q >> 1, h = q & 1;
    if (t < 128) ctb[t] = cosf(time_b[t]);
    __syncthreads();
    if (t < 128) {
      int e = h*128 + t;
      float a = bq[l*256 + e];
      const float* wq = Wq + l*65536 + e*256 + 128;
      for (int m = 0; m < 128; m++) a += wq[m]*ctb[m];
      sqc[t] = a;
    }
    __syncthreads();
    { float s = 0.f;      // gc
      const float* wk = Wk + l*65536 + h*32768 + t;
      for (int m = 0; m < 128; m++) s += sqc[m]*wk[m*256];
      ws[OFF_GC + l*512 + h*256 + t] = s; }
    if (t < 128) {        // u
      float s = 0.f;
      const float* wq = Wq + l*65536 + h*32768 + t;
      const float* bkp = bk + l*256 + h*128;
      for (int m = 0; m < 128; m++) s += wq[m*256]*bkp[m];
      ws[OFF_U + (l*2+h)*128 + t] = s; }
    if (t == 254) {       // cc
      float s = 0.f;
      const float* bkp = bk + l*256 + h*128;
      for (int m = 0; m < 128; m++) s += sqc[m]*bkp[m];
      ws[OFF_CC + l*2+h] = s; }
  }
}

__global__ __launch_bounds__(256) void packw(
    const float* __restrict__ Wv, const float* __restrict__ Wo,
    const float* __restrict__ W1, const float* __restrict__ W2,
    float* __restrict__ ws)
{
  int idx = blockIdx.x*256 + threadIdx.x;   // < 393216
  ushort* wsu = (ushort*)(ws + OFF_PKF);
  if (idx == 0) *(int*)(ws + OFF_CNT) = 0;
  if (idx < 131072) {          // VPK
    int q = idx >> 15, r = idx & 32767, l = q >> 1, h = q & 1;
    int bb = r & 7, lane = (r >> 3) & 63, kk = (r >> 9) & 7, nt = r >> 12;
    int k = kk*32 + (lane>>4)*8 + bb, d = nt*16 + (lane&15);
    wsu[VPKo + idx] = cvth(Wv[l*65536 + (h*128+d)*256 + k]);
  } else if (idx < 262144) {   // OPK
    int rel = idx - 131072, l = rel >> 16, r = rel & 65535;
    int bb = r & 7, lane = (r >> 3) & 63, kk = (r >> 9) & 7, nt = r >> 12;
    int k = kk*32 + (lane>>4)*8 + bb, e = nt*16 + (lane&15);
    wsu[OPKo + rel] = cvth(Wo[l*65536 + e*256 + k]);
  } else if (idx < 360448) {   // W1PK
    int rel = idx - 262144, l = rel / 49152, r = rel % 49152;
    int nt = r / 6144, rr = r - nt*6144;
    int kk = rr >> 9, lane = (rr >> 3) & 63, bb = rr & 7;
    int k = kk*32 + (lane>>4)*8 + bb, d = nt*16 + (lane&15);
    wsu[W1PKo + rel] = cvth(W1[l*49152 + d*384 + k]);
  } else {                     // W2PK
    int rel = idx - 360448, l = rel >> 14, r = rel & 16383;
    int nt = r >> 11, rr = r & 2047;
    int kk = rr >> 9, lane = (rr >> 3) & 63, bb = rr & 7;
    int k = kk*32 + (lane>>4)*8 + bb, d = nt*16 + (lane&15);
    wsu[W2PKo + rel] = cvth(W2[l*16384 + d*128 + k]);
  }
}

__global__ __launch_bounds__(256) void pack_emb(
    const float* __restrict__ emb, float* __restrict__ ws)
{
  int idx = blockIdx.x*256 + threadIdx.x;   // < 1600000
  if (idx < 1600000) {
    float4 a = ((const float4*)emb)[idx*2];
    float4 b = ((const float4*)emb)[idx*2+1];
    ushort8 o;
    o[0]=cvth(a.x); o[1]=cvth(a.y); o[2]=cvth(a.z); o[3]=cvth(a.w);
    o[4]=cvth(b.x); o[5]=cvth(b.y); o[6]=cvth(b.z); o[7]=cvth(b.w);
    ((ushort8*)(ws + OFF_UEB))[idx] = o;
  }
}

__global__ __launch_bounds__(256) void compact_valid(
    const int* __restrict__ edges, const int* __restrict__ u_mask,
    float* __restrict__ ws)
{
  int idx = blockIdx.x*256 + threadIdx.x;    // < 40960
  int b = idx / K, s = idx - b*K;
  int pe = edges[b];
  if (u_mask[pe*TBL + (TBL-K) + s] > 0) {
    int pos = atomicAdd((int*)(ws + OFF_CNT), 1);
    ((int*)(ws + OFF_CNT))[1 + pos] = idx;
  }
}

template<int LAYER, bool NBF16>
__global__ __launch_bounds__(256, 3) void attend(
    const int* __restrict__ nodes, const int* __restrict__ edges, const int* __restrict__ tstamps,
    const int* __restrict__ u_edges, const int* __restrict__ u_neig,
    const int* __restrict__ u_times, const int* __restrict__ u_mask,
    const int* __restrict__ i_neig, const int* __restrict__ i_times, const int* __restrict__ i_mask,
    const float* __restrict__ user_emb, const float* __restrict__ item_emb,
    const float* __restrict__ time_w, const float* __restrict__ time_b,
    const float* __restrict__ bv, const float* __restrict__ bo,
    const float* __restrict__ b1, const float* __restrict__ b2,
    float* __restrict__ wsf, float* __restrict__ out)
{
  __shared__ __align__(16) ushort sOP2[16*392];  // [oo(256) | feat(128) | pad]  (f16)
  __shared__ __align__(16) ushort sGWS[16*520];  // g then wsum (f16)
  __shared__ __align__(16) ushort sOP1[16*264];  // o then h1 (f16)
  __shared__ float sTW[128], sTB[128], sAL[640], sQB[32];
  __shared__ int imem[96];
  __shared__ int nbm[960];

  const int tid = threadIdx.x, blk = blockIdx.x, l = LAYER;
  const int lane = tid & 63, wv = tid >> 6;
  const int col = lane & 15, chunk = lane >> 4;
  const ushort* wsu = (const ushort*)(wsf + OFF_PKF);
  const ushort* nbu = NBF16 ? ((LAYER == 0) ? (const ushort*)(wsf + OFF_UEB)
                                            : (const ushort*)(wsf + OFF_NBRB))
                            : (const ushort*)nullptr;
  const float*  nbf = user_emb;  // f32 fallback (LAYER==0 only)
  ushort* nbrOut = (ushort*)(wsf + OFF_NBRB);

  int count = (LAYER == 0) ? *(const int*)(wsf + OFF_CNT) : NB_B;
  if (blk*G >= count) return;

  if (tid < G) {
    int idx = blk*G + tid; int act = idx < count ? 1 : 0;
    int slot, nid, ntm, erow;
    if (LAYER == 0) {
      int ii = act ? idx : 0;
      slot = ((const int*)(wsf + OFF_CNT))[1 + ii];
      int bb = slot / K, s = slot - bb*K;
      int base = edges[bb]*TBL + (TBL-K) + s;
      nid = u_neig[base]; ntm = u_times[base]; erow = u_edges[base];
    } else { slot = idx; nid = nodes[idx]; ntm = tstamps[idx]; erow = edges[idx]; }
    imem[tid] = nid; imem[16+tid] = ntm; imem[32+tid] = erow;
    imem[48+tid] = slot; imem[80+tid] = act;
  }
  if (tid < 128) { sTW[tid] = time_w[tid]; sTB[tid] = time_b[tid]; }
  __syncthreads();

  // P0: gather feat -> OP2 cols 256..383 (f16); neighbor meta
  const float* nemb = (LAYER == 0) ? item_emb : user_emb;
  #pragma unroll
  for (int it = 0; it < 8; it++) {
    int idx = tid + it*256, n = idx >> 7, i = idx & 127;
    sOP2[n*392 + 256 + i] = cvth(nemb[(long)imem[n]*D + i]);
  }
  #pragma unroll
  for (int it = 0; it < 2; it++) {
    int p = tid + it*256;
    if (p < G*K) {
      int n = p / K, k = p - n*K;
      int base = imem[32+n]*TBL + (TBL-K) + k;
      if (LAYER == 0) { nbm[p] = i_neig[base]; nbm[320+p] = i_times[base]; nbm[640+p] = i_mask[base]; }
      else            { nbm[p] = (blk*G+n)*K + k; nbm[320+p] = u_times[base]; nbm[640+p] = u_mask[base]; }
    }
  }
  __syncthreads();

  // G1: g[16x512] = feat[16x128] @ A (+gc) -> sGWS f16
  {
    half8 a[4];
    #pragma unroll
    for (int kk = 0; kk < 4; kk++)
      a[kk] = ldh8(&sOP2[col*392 + 256 + kk*32 + chunk*8]);
    f32x4 acc[8];
    #pragma unroll
    for (int t = 0; t < 8; t++) acc[t] = (f32x4){0.f,0.f,0.f,0.f};
    const ushort* BP = wsu + APKo + (long)l*65536;
    #pragma unroll
    for (int t = 0; t < 8; t++) {
      int nt = wv*8 + t;
      #pragma unroll
      for (int kk = 0; kk < 4; kk++) {
        half8 b = ldh8(&BP[((nt*4+kk)*64 + lane)*8]);
        acc[t] = __builtin_amdgcn_mfma_f32_16x16x32_f16(a[kk], b, acc[t], 0, 0, 0);
      }
    }
    #pragma unroll
    for (int t = 0; t < 8; t++) {
      int N = (wv*8+t)*16 + col;
      float gcv = wsf[OFF_GC + l*512 + N];
      #pragma unroll
      for (int r = 0; r < 4; r++)
        sGWS[(chunk*4+r)*520 + N] = cvth(acc[t][r] + gcv);
    }
  }
  if (tid < 32) {   // qb[n][h]
    int n = tid >> 1, h = tid & 1;
    float s = wsf[OFF_CC + l*2 + h];
    const float* u = wsf + OFF_U + (l*2+h)*128;
    for (int i = 0; i < 128; i++) s += h2f(sOP2[n*392 + 256 + i])*u[i];
    sQB[tid] = s;
  }
  __syncthreads();

  // Phase A: 320 scores. Pass1: 256 items 1:1; Pass2: 64 items split 4 lanes each.
  {
    auto scorePart = [&](int p, int c0, int c1, float& r0, float& r1) {
      int n = p / K;
      float dtf = (float)(imem[16+n] - nbm[320+p]);
      const __half2* gp2 = (const __half2*)&sGWS[n*520];
      __half2 z = __floats2half2_rn(0.f, 0.f);
      __half2 A0 = z, B0 = z, A1 = z, B1 = z;
      if constexpr (NBF16) {
        const __half2* fr2 = (const __half2*)(nbu + (long)nbm[p]*D);
        for (int c = c0; c < c1; c++) {
          __half2 f0 = fr2[c*4+0], f1 = fr2[c*4+1];
          __half2 f2 = fr2[c*4+2], f3 = fr2[c*4+3];
          A0 = __hfma2(f0, gp2[c*4+0], A0);     B0 = __hfma2(f1, gp2[c*4+1], B0);
          A0 = __hfma2(f2, gp2[c*4+2], A0);     B0 = __hfma2(f3, gp2[c*4+3], B0);
          A1 = __hfma2(f0, gp2[128+c*4+0], A1); B1 = __hfma2(f1, gp2[128+c*4+1], B1);
          A1 = __hfma2(f2, gp2[128+c*4+2], A1); B1 = __hfma2(f3, gp2[128+c*4+3], B1);
        }
      } else {
        const float* fr = nbf + (long)nbm[p]*D;
        for (int c = c0; c < c1; c++) {
          __half2 f0 = __floats2half2_rn(fr[c*8+0], fr[c*8+1]);
          __half2 f1 = __floats2half2_rn(fr[c*8+2], fr[c*8+3]);
          __half2 f2 = __floats2half2_rn(fr[c*8+4], fr[c*8+5]);
          __half2 f3 = __floats2half2_rn(fr[c*8+6], fr[c*8+7]);
          A0 = __hfma2(f0, gp2[c*4+0], A0);     B0 = __hfma2(f1, gp2[c*4+1], B0);
          A0 = __hfma2(f2, gp2[c*4+2], A0);     B0 = __hfma2(f3, gp2[c*4+3], B0);
          A1 = __hfma2(f0, gp2[128+c*4+0], A1); B1 = __hfma2(f1, gp2[128+c*4+1], B1);
          A1 = __hfma2(f2, gp2[128+c*4+2], A1); B1 = __hfma2(f3, gp2[128+c*4+3], B1);
        }
      }
      for (int c = c0; c < c1; c++) {
        int j = c*8;
        __half2 cA = __floats2half2_rn(
            cosr(__fadd_rn(__fmul_rn(dtf, sTW[j+0]), sTB[j+0])),
            cosr(__fadd_rn(__fmul_rn(dtf, sTW[j+1]), sTB[j+1])));
        __half2 cB = __floats2half2_rn(
            cosr(__fadd_rn(__fmul_rn(dtf, sTW[j+2]), sTB[j+2])),
            cosr(__fadd_rn(__fmul_rn(dtf, sTW[j+3]), sTB[j+3])));
        __half2 cC = __floats2half2_rn(
            cosr(__fadd_rn(__fmul_rn(dtf, sTW[j+4]), sTB[j+4])),
            cosr(__fadd_rn(__fmul_rn(dtf, sTW[j+5]), sTB[j+5])));
        __half2 cD = __floats2half2_rn(
            cosr(__fadd_rn(__fmul_rn(dtf, sTW[j+6]), sTB[j+6])),
            cosr(__fadd_rn(__fmul_rn(dtf, sTW[j+7]), sTB[j+7])));
        A0 = __hfma2(cA, gp2[64+c*4+0], A0);     B0 = __hfma2(cB, gp2[64+c*4+1], B0);
        A0 = __hfma2(cC, gp2[64+c*4+2], A0);     B0 = __hfma2(cD, gp2[64+c*4+3], B0);
        A1 = __hfma2(cA, gp2[192+c*4+0], A1);    B1 = __hfma2(cB, gp2[192+c*4+1], B1);
        A1 = __hfma2(cC, gp2[192+c*4+2], A1);    B1 = __hfma2(cD, gp2[192+c*4+3], B1);
      }
      __half2 S0 = __hadd2(A0, B0), S1 = __hadd2(A1, B1);
      r0 = __low2float(S0) + __high2float(S0);
      r1 = __low2float(S1) + __high2float(S1);
    };
    const float invsq = 0.08838834764831845f;
    {   // pass 1: items 0..255
      int p = tid;
      float a0, a1;
      scorePart(p, 0, 16, a0, a1);
      int n = p / K, k = p - n*K;
      int m = nbm[640+p];
      sAL[n*40 + k]      = m > 0 ? (a0 + sQB[n*2])*invsq   : -1e9f;
      sAL[n*40 + 20 + k] = m > 0 ? (a1 + sQB[n*2+1])*invsq : -1e9f;
    }
    {   // pass 2: items 256..319, 4 lanes per item
      int p = 256 + (tid >> 2), sub = tid & 3;
      float a0, a1;
      scorePart(p, sub*4, sub*4+4, a0, a1);
      a0 += __shfl_xor(a0, 1); a0 += __shfl_xor(a0, 2);
      a1 += __shfl_xor(a1, 1); a1 += __shfl_xor(a1, 2);
      if (sub == 0) {
        int n = p / K, k = p - n*K;
        int m = nbm[640+p];
        sAL[n*40 + k]      = m > 0 ? (a0 + sQB[n*2])*invsq   : -1e9f;
        sAL[n*40 + 20 + k] = m > 0 ? (a1 + sQB[n*2+1])*invsq : -1e9f;
      }
    }
  }
  __syncthreads();

  // softmax
  if (tid < 2*G) {
    int n = tid >> 1, h = tid & 1;
    float* a = &sAL[n*40 + h*20];
    float mx = -1e30f;
    for (int k = 0; k < K; k++) mx = fmaxf(mx, a[k]);
    float s = 0.f;
    for (int k = 0; k < K; k++) { float e = __expf(a[k]-mx); a[k] = e; s += e; }
    float inv = 1.f/s;
    for (int k = 0; k < K; k++) a[k] *= inv;
    if (h == 0) { int any = 0;
      for (int k = 0; k < K; k++) any |= nbm[640 + n*20 + k];
      imem[64+n] = any; }
  }
  __syncthreads();

  // Phase C: wsum -> sGWS f16; thread owns 8 contiguous dims; packed half2 accum
  {
    const int n = tid >> 4, e0 = tid & 15;
    __half2 z = __floats2half2_rn(0.f, 0.f);
    __half2 W0[4], W1[4];
    #pragma unroll
    for (int i = 0; i < 4; i++) { W0[i] = z; W1[i] = z; }
    #pragma unroll 4
    for (int k = 0; k < K; k++) {
      __half2 a0h = __half2half2(__float2half(sAL[n*40 + k]));
      __half2 a1h = __half2half2(__float2half(sAL[n*40 + 20 + k]));
      if constexpr (NBF16) {
        const __half2* f2 = (const __half2*)(nbu + (long)nbm[n*20+k]*D + e0*8);
        #pragma unroll
        for (int i = 0; i < 4; i++) {
          __half2 f = f2[i];
          W0[i] = __hfma2(a0h, f, W0[i]);
          W1[i] = __hfma2(a1h, f, W1[i]);
        }
      } else {
        const float* fr = nbf + (long)nbm[n*20+k]*D + e0*8;
        #pragma unroll
        for (int i = 0; i < 4; i++) {
          __half2 f = __floats2half2_rn(fr[2*i], fr[2*i+1]);
          W0[i] = __hfma2(a0h, f, W0[i]);
          W1[i] = __hfma2(a1h, f, W1[i]);
        }
      }
    }
    #pragma unroll
    for (int i = 0; i < 4; i++) {
      *(__half2*)&sGWS[n*520 + e0*8 + 2*i]       = W0[i];
      *(__half2*)&sGWS[n*520 + 256 + e0*8 + 2*i] = W1[i];
    }
    // time part
    #pragma unroll
    for (int i = 0; i < 4; i++) { W0[i] = z; W1[i] = z; }
    float twv[8], tbv[8];
    #pragma unroll
    for (int i = 0; i < 8; i++) { twv[i] = sTW[e0*8+i]; tbv[i] = sTB[e0*8+i]; }
    for (int k = 0; k < K; k++) {
      __half2 a0h = __half2half2(__float2half(sAL[n*40 + k]));
      __half2 a1h = __half2half2(__float2half(sAL[n*40 + 20 + k]));
      float dtf = (float)(imem[16+n] - nbm[320 + n*20 + k]);
      #pragma unroll
      for (int i = 0; i < 4; i++) {
        __half2 c2 = __floats2half2_rn(
            cosr(__fadd_rn(__fmul_rn(dtf, twv[2*i]),   tbv[2*i])),
            cosr(__fadd_rn(__fmul_rn(dtf, twv[2*i+1]), tbv[2*i+1])));
        W0[i] = __hfma2(a0h, c2, W0[i]);
        W1[i] = __hfma2(a1h, c2, W1[i]);
      }
    }
    #pragma unroll
    for (int i = 0; i < 4; i++) {
      *(__half2*)&sGWS[n*520 + 128 + e0*8 + 2*i] = W0[i];
      *(__half2*)&sGWS[n*520 + 384 + e0*8 + 2*i] = W1[i];
    }
  }
  __syncthreads();

  // G2: o = wsum_h @ Wv_h (+bv) -> sOP1
  {
    int h = wv >> 1, ntb = (wv & 1)*4;
    half8 a[8];
    #pragma unroll
    for (int kk = 0; kk < 8; kk++)
      a[kk] = ldh8(&sGWS[col*520 + h*256 + kk*32 + chunk*8]);
    f32x4 acc[4];
    #pragma unroll
    for (int t = 0; t < 4; t++) acc[t] = (f32x4){0.f,0.f,0.f,0.f};
    const ushort* BP = wsu + VPKo + (long)(l*2+h)*32768;
    #pragma unroll
    for (int t = 0; t < 4; t++) {
      int nt = ntb + t;
      #pragma unroll
      for (int kk = 0; kk < 8; kk++) {
        half8 b = ldh8(&BP[((nt*8+kk)*64 + lane)*8]);
        acc[t] = __builtin_amdgcn_mfma_f32_16x16x32_f16(a[kk], b, acc[t], 0, 0, 0);
      }
    }
    #pragma unroll
    for (int t = 0; t < 4; t++) {
      int ocol = h*128 + (ntb+t)*16 + col;
      float bb = bv[l*256 + ocol];
      #pragma unroll
      for (int r = 0; r < 4; r++)
        sOP1[(chunk*4+r)*264 + ocol] = cvth(acc[t][r] + bb);
    }
  }
  __syncthreads();

  // G3: oo = o @ Wo (+bo, anyv mask) -> sOP2 cols 0..255
  {
    half8 a[8];
    #pragma unroll
    for (int kk = 0; kk < 8; kk++)
      a[kk] = ldh8(&sOP1[col*264 + kk*32 + chunk*8]);
    f32x4 acc[4];
    #pragma unroll
    for (int t = 0; t < 4; t++) acc[t] = (f32x4){0.f,0.f,0.f,0.f};
    const ushort* BP = wsu + OPKo + (long)l*65536;
    #pragma unroll
    for (int t = 0; t < 4; t++) {
      int nt = wv*4 + t;
      #pragma unroll
      for (int kk = 0; kk < 8; kk++) {
        half8 b = ldh8(&BP[((nt*8+kk)*64 + lane)*8]);
        acc[t] = __builtin_amdgcn_mfma_f32_16x16x32_f16(a[kk], b, acc[t], 0, 0, 0);
      }
    }
    #pragma unroll
    for (int t = 0; t < 4; t++) {
      int e = (wv*4+t)*16 + col;
      float bb = bo[l*256 + e];
      #pragma unroll
      for (int r = 0; r < 4; r++) {
        int row = chunk*4 + r;
        float v = imem[64+row] ? (acc[t][r] + bb) : 0.f;
        sOP2[row*392 + e] = cvth(v);
      }
    }
  }
  __syncthreads();

  // G4: h1 = [oo,feat] @ W1 (+b1, relu) -> sOP1 cols 0..127
  {
    half8 a[12];
    #pragma unroll
    for (int kk = 0; kk < 12; kk++)
      a[kk] = ldh8(&sOP2[col*392 + kk*32 + chunk*8]);
    f32x4 acc[2];
    acc[0] = (f32x4){0.f,0.f,0.f,0.f}; acc[1] = (f32x4){0.f,0.f,0.f,0.f};
    const ushort* BP = wsu + W1PKo + (long)l*49152;
    #pragma unroll
    for (int t = 0; t < 2; t++) {
      int nt = wv*2 + t;
      #pragma unroll
      for (int kk = 0; kk < 12; kk++) {
        half8 b = ldh8(&BP[((nt*12+kk)*64 + lane)*8]);
        acc[t] = __builtin_amdgcn_mfma_f32_16x16x32_f16(a[kk], b, acc[t], 0, 0, 0);
      }
    }
    #pragma unroll
    for (int t = 0; t < 2; t++) {
      int dcol = (wv*2+t)*16 + col;
      float bb = b1[l*128 + dcol];
      #pragma unroll
      for (int r = 0; r < 4; r++)
        sOP1[(chunk*4+r)*264 + dcol] = cvth(fmaxf(acc[t][r] + bb, 0.f));
    }
  }
  __syncthreads();

  // G5: out = h1 @ W2 (+b2) -> NBR f16 (L0) or global f32 (L1)
  {
    half8 a[4];
    #pragma unroll
    for (int kk = 0; kk < 4; kk++)
      a[kk] = ldh8(&sOP1[col*264 + kk*32 + chunk*8]);
    f32x4 acc[2];
    acc[0] = (f32x4){0.f,0.f,0.f,0.f}; acc[1] = (f32x4){0.f,0.f,0.f,0.f};
    const ushort* BP = wsu + W2PKo + (long)l*16384;
    #pragma unroll
    for (int t = 0; t < 2; t++) {
      int nt = wv*2 + t;
      #pragma unroll
      for (int kk = 0; kk < 4; kk++) {
        half8 b = ldh8(&BP[((nt*4+kk)*64 + lane)*8]);
        acc[t] = __builtin_amdgcn_mfma_f32_16x16x32_f16(a[kk], b, acc[t], 0, 0, 0);
      }
    }
    #pragma unroll
    for (int t = 0; t < 2; t++) {
      int dcol = (wv*2+t)*16 + col;
      float bb = b2[l*128 + dcol];
      #pragma unroll
      for (int r = 0; r < 4; r++) {
        int row = chunk*4 + r;
        float v = acc[t][r] + bb;
        if (LAYER == 0) { if (imem[80+row]) nbrOut[(long)imem[48+row]*D + dcol] = cvth(v); }
        else            out[(long)(blk*G + row)*D + dcol] = v;
      }
    }
  }
}

extern "C" void kernel_launch(void* const* d_in, const int* in_sizes, int n_in,
                              void* d_out, int out_size, void* d_ws, size_t ws_size,
                              hipStream_t stream) {
  const int* nodes  = (const int*)d_in[0];
  const int* edges  = (const int*)d_in[1];
  const int* tst    = (const int*)d_in[2];
  const int* u_neig = (const int*)d_in[4];
  const int* u_edges= (const int*)d_in[5];
  const int* u_times= (const int*)d_in[6];
  const int* u_mask = (const int*)d_in[7];
  const int* i_neig = (const int*)d_in[8];
  const int* i_times= (const int*)d_in[10];
  const int* i_mask = (const int*)d_in[11];
  const float* user_emb = (const float*)d_in[12];
  const float* item_emb = (const float*)d_in[13];
  const float* time_w = (const float*)d_in[14];
  const float* time_b = (const float*)d_in[15];
  const float* Wq = (const float*)d_in[16]; const float* bq = (const float*)d_in[17];
  const float* Wk = (const float*)d_in[18]; const float* bk = (const float*)d_in[19];
  const float* Wv = (const float*)d_in[20]; const float* bv = (const float*)d_in[21];
  const float* Wo = (const float*)d_in[22]; const float* bo = (const float*)d_in[23];
  const float* W1 = (const float*)d_in[24]; const float* b1 = (const float*)d_in[25];
  const float* W2 = (const float*)d_in[26]; const float* b2 = (const float*)d_in[27];
  float* ws = (float*)d_ws;
  float* out = (float*)d_out;

  bool emb16 = ws_size >= (size_t)WS_NEED_F * 4;

  precompute2<<<dim3(516), dim3(256), 0, stream>>>(Wq, Wk, bq, bk, time_b, ws);
  packw<<<dim3(1536), dim3(256), 0, stream>>>(Wv, Wo, W1, W2, ws);
  if (emb16) pack_emb<<<dim3(6250), dim3(256), 0, stream>>>(user_emb, ws);
  compact_valid<<<dim3(160), dim3(256), 0, stream>>>(edges, u_mask, ws);

  if (emb16)
    attend<0,true><<<dim3(NSLOT/G), dim3(256), 0, stream>>>(
        nodes, edges, tst, u_edges, u_neig, u_times, u_mask,
        i_neig, i_times, i_mask, user_emb, item_emb, time_w, time_b,
        bv, bo, b1, b2, ws, out);
  else
    attend<0,false><<<dim3(NSLOT/G), dim3(256), 0, stream>>>(
        nodes, edges, tst, u_edges, u_neig, u_times, u_mask,
        i_neig, i_times, i_mask, user_emb, item_emb, time_w, time_b,
        bv, bo, b1, b2, ws, out);

  attend<1,true><<<dim3(NB_B/G), dim3(256), 0, stream>>>(
      nodes, edges, tst, u_edges, u_neig, u_times, u_mask,
      i_neig, i_times, i_mask, user_emb, item_emb, time_w, time_b,
      bv, bo, b1, b2, ws, out);
}

// Round 13
// 138.058 us; speedup vs baseline: 1.7538x; 1.0379x over previous
//
#include <hip/hip_runtime.h>
#include <hip/hip_bf16.h>
#include <hip/hip_fp16.h>

#define TBL 50
#define K 20
#define D 128
#define E 256
#define NB_B 2048
#define NSLOT (NB_B*K)     // 40960
#define G 16

typedef unsigned short ushort;
typedef unsigned short ushort8 __attribute__((ext_vector_type(8)));
typedef float f32x4 __attribute__((ext_vector_type(4)));
typedef _Float16 half8 __attribute__((ext_vector_type(8)));

// ws float offsets
#define OFF_GC    0              // [l2][512] f32
#define OFF_U     1024           // [l2*2][128] f32
#define OFF_CC    1536           // [4] f32
#define OFF_PKF   2052           // packed f16 weights (524288 ushorts)
#define OFF_NBRB  264196         // NBR f16 [40960][128] ushorts
#define OFF_CNT   2885636        // int count; int compact[40960]
#define OFF_UEB   2926600        // user_emb f16 [100000][128] ushorts
#define WS_NEED_F (OFF_UEB + 6400000)
// ushort offsets inside PK region
#define APKo   0
#define VPKo   131072
#define OPKo   262144
#define W1PKo  393216
#define W2PKo  491520

__device__ __forceinline__ float cosr(float x) {
  const float HI = 0.15915493667125702f;   // fl(1/2pi)
  const float LO = 6.4206383e-9f;
  float k = rintf(x * HI);
  float f = __fmaf_rn(x, HI, -k);
  f = __fmaf_rn(x, LO, f);
  return __builtin_amdgcn_cosf(f);         // v_cos_f32 (revolutions)
}
__device__ __forceinline__ ushort cvth(float f) {
  union { _Float16 h; ushort u; } c; c.h = (_Float16)f; return c.u;
}
__device__ __forceinline__ float h2f(ushort u) {
  union { ushort u; _Float16 h; } c; c.u = u; return (float)c.h;
}
__device__ __forceinline__ half8 ldh8(const ushort* p) {
  union { ushort8 u; half8 h; } c;
  c.u = *(const ushort8*)p;
  return c.h;
}

// Fused preprocessing: blocks [0,516) = A/gc/u/cc; [516,2052) = weight pack;
// [2052,8302) = user_emb f16 pack.
__global__ __launch_bounds__(256) void prep(
    const float* __restrict__ Wq, const float* __restrict__ Wk,
    const float* __restrict__ bq, const float* __restrict__ bk,
    const float* __restrict__ time_b,
    const float* __restrict__ Wv, const float* __restrict__ Wo,
    const float* __restrict__ W1, const float* __restrict__ W2,
    const float* __restrict__ user_emb, float* __restrict__ ws)
{
  __shared__ float sqc[128], ctb[128];
  int b = blockIdx.x, t = threadIdx.x;
  ushort* wsu = (ushort*)(ws + OFF_PKF);
  if (b < 512) {           // A[l][h][i][j] -> APK f16
    int l = b >> 8, h = (b >> 7) & 1, i = b & 127;
    float s = 0.f;
    const float* wq = Wq + l*65536 + h*32768 + i;
    const float* wk = Wk + l*65536 + h*32768 + t;
    for (int m = 0; m < 128; m++) s += wq[m*256]*wk[m*256];
    int N = h*256 + t;
    int nt = N >> 4, cl = N & 15;
    int kk = i >> 5, ch = (i >> 3) & 3, bb = i & 7;
    wsu[APKo + (long)l*65536 + (((nt*4+kk)*64 + ch*16 + cl)*8) + bb] = cvth(s);
  } else if (b < 516) {
    int q = b - 512, l = q >> 1, h = q & 1;
    if (t < 128) ctb[t] = cosf(time_b[t]);
    __syncthreads();
    if (t < 128) {
      int e = h*128 + t;
      float a = bq[l*256 + e];
      const float* wq = Wq + l*65536 + e*256 + 128;
      for (int m = 0; m < 128; m++) a += wq[m]*ctb[m];
      sqc[t] = a;
    }
    __syncthreads();
    { float s = 0.f;      // gc
      const float* wk = Wk + l*65536 + h*32768 + t;
      for (int m = 0; m < 128; m++) s += sqc[m]*wk[m*256];
      ws[OFF_GC + l*512 + h*256 + t] = s; }
    if (t < 128) {        // u
      float s = 0.f;
      const float* wq = Wq + l*65536 + h*32768 + t;
      const float* bkp = bk + l*256 + h*128;
      for (int m = 0; m < 128; m++) s += wq[m*256]*bkp[m];
      ws[OFF_U + (l*2+h)*128 + t] = s; }
    if (t == 254) {       // cc
      float s = 0.f;
      const float* bkp = bk + l*256 + h*128;
      for (int m = 0; m < 128; m++) s += sqc[m]*bkp[m];
      ws[OFF_CC + l*2+h] = s; }
  } else if (b < 2052) {   // weight pack
    int idx = (b - 516)*256 + t;   // < 393216
    if (idx == 0) *(int*)(ws + OFF_CNT) = 0;
    if (idx < 131072) {          // VPK
      int q = idx >> 15, r = idx & 32767, l = q >> 1, h = q & 1;
      int bb = r & 7, lane = (r >> 3) & 63, kk = (r >> 9) & 7, nt = r >> 12;
      int k = kk*32 + (lane>>4)*8 + bb, d = nt*16 + (lane&15);
      wsu[VPKo + idx] = cvth(Wv[l*65536 + (h*128+d)*256 + k]);
    } else if (idx < 262144) {   // OPK
      int rel = idx - 131072, l = rel >> 16, r = rel & 65535;
      int bb = r & 7, lane = (r >> 3) & 63, kk = (r >> 9) & 7, nt = r >> 12;
      int k = kk*32 + (lane>>4)*8 + bb, e = nt*16 + (lane&15);
      wsu[OPKo + rel] = cvth(Wo[l*65536 + e*256 + k]);
    } else if (idx < 360448) {   // W1PK
      int rel = idx - 262144, l = rel / 49152, r = rel % 49152;
      int nt = r / 6144, rr = r - nt*6144;
      int kk = rr >> 9, lane = (rr >> 3) & 63, bb = rr & 7;
      int k = kk*32 + (lane>>4)*8 + bb, d = nt*16 + (lane&15);
      wsu[W1PKo + rel] = cvth(W1[l*49152 + d*384 + k]);
    } else {                     // W2PK
      int rel = idx - 360448, l = rel >> 14, r = rel & 16383;
      int nt = r >> 11, rr = r & 2047;
      int kk = rr >> 9, lane = (rr >> 3) & 63, bb = rr & 7;
      int k = kk*32 + (lane>>4)*8 + bb, d = nt*16 + (lane&15);
      wsu[W2PKo + rel] = cvth(W2[l*16384 + d*128 + k]);
    }
  } else {                 // user_emb pack
    int idx = (b - 2052)*256 + t;  // < 1600000
    float4 a = ((const float4*)user_emb)[idx*2];
    float4 bb = ((const float4*)user_emb)[idx*2+1];
    ushort8 o;
    o[0]=cvth(a.x); o[1]=cvth(a.y); o[2]=cvth(a.z); o[3]=cvth(a.w);
    o[4]=cvth(bb.x); o[5]=cvth(bb.y); o[6]=cvth(bb.z); o[7]=cvth(bb.w);
    ((ushort8*)(ws + OFF_UEB))[idx] = o;
  }
}

__global__ __launch_bounds__(256) void compact_valid(
    const int* __restrict__ edges, const int* __restrict__ u_mask,
    float* __restrict__ ws)
{
  int idx = blockIdx.x*256 + threadIdx.x;    // < 40960
  int b = idx / K, s = idx - b*K;
  int pe = edges[b];
  if (u_mask[pe*TBL + (TBL-K) + s] > 0) {
    int pos = atomicAdd((int*)(ws + OFF_CNT), 1);
    ((int*)(ws + OFF_CNT))[1 + pos] = idx;
  }
}

template<int LAYER, bool NBF16>
__global__ __launch_bounds__(256, 3) void attend(
    const int* __restrict__ nodes, const int* __restrict__ edges, const int* __restrict__ tstamps,
    const int* __restrict__ u_edges, const int* __restrict__ u_neig,
    const int* __restrict__ u_times, const int* __restrict__ u_mask,
    const int* __restrict__ i_neig, const int* __restrict__ i_times, const int* __restrict__ i_mask,
    const float* __restrict__ user_emb, const float* __restrict__ item_emb,
    const float* __restrict__ time_w, const float* __restrict__ time_b,
    const float* __restrict__ bv, const float* __restrict__ bo,
    const float* __restrict__ b1, const float* __restrict__ b2,
    float* __restrict__ wsf, float* __restrict__ out)
{
  __shared__ __align__(16) ushort sOP2[16*392];  // [oo(256) | feat(128) | pad]  (f16)
  __shared__ __align__(16) ushort sGWS[16*520];  // g then wsum (f16)
  __shared__ __align__(16) ushort sOP1[16*264];  // o then h1 (f16)
  __shared__ float sTW[128], sTB[128], sAL[640], sQB[32];
  __shared__ ushort sALh[640];                   // f16 copy of softmax weights
  __shared__ int imem[96];
  __shared__ int nbm[960];

  const int tid = threadIdx.x, blk = blockIdx.x, l = LAYER;
  const int lane = tid & 63, wv = tid >> 6;
  const int col = lane & 15, chunk = lane >> 4;
  const ushort* wsu = (const ushort*)(wsf + OFF_PKF);
  const ushort* nbu = NBF16 ? ((LAYER == 0) ? (const ushort*)(wsf + OFF_UEB)
                                            : (const ushort*)(wsf + OFF_NBRB))
                            : (const ushort*)nullptr;
  const float*  nbf = user_emb;  // f32 fallback (LAYER==0 only)
  ushort* nbrOut = (ushort*)(wsf + OFF_NBRB);

  int count = (LAYER == 0) ? *(const int*)(wsf + OFF_CNT) : NB_B;
  if (blk*G >= count) return;

  if (tid < G) {
    int idx = blk*G + tid; int act = idx < count ? 1 : 0;
    int slot, nid, ntm, erow;
    if (LAYER == 0) {
      int ii = act ? idx : 0;
      slot = ((const int*)(wsf + OFF_CNT))[1 + ii];
      int bb = slot / K, s = slot - bb*K;
      int base = edges[bb]*TBL + (TBL-K) + s;
      nid = u_neig[base]; ntm = u_times[base]; erow = u_edges[base];
    } else { slot = idx; nid = nodes[idx]; ntm = tstamps[idx]; erow = edges[idx]; }
    imem[tid] = nid; imem[16+tid] = ntm; imem[32+tid] = erow;
    imem[48+tid] = slot; imem[80+tid] = act;
  }
  if (tid < 128) { sTW[tid] = time_w[tid]; sTB[tid] = time_b[tid]; }
  __syncthreads();

  // P0: gather feat -> OP2 cols 256..383 (f16); neighbor meta
  const float* nemb = (LAYER == 0) ? item_emb : user_emb;
  #pragma unroll
  for (int it = 0; it < 8; it++) {
    int idx = tid + it*256, n = idx >> 7, i = idx & 127;
    sOP2[n*392 + 256 + i] = cvth(nemb[(long)imem[n]*D + i]);
  }
  #pragma unroll
  for (int it = 0; it < 2; it++) {
    int p = tid + it*256;
    if (p < G*K) {
      int n = p / K, k = p - n*K;
      int base = imem[32+n]*TBL + (TBL-K) + k;
      if (LAYER == 0) { nbm[p] = i_neig[base]; nbm[320+p] = i_times[base]; nbm[640+p] = i_mask[base]; }
      else            { nbm[p] = (blk*G+n)*K + k; nbm[320+p] = u_times[base]; nbm[640+p] = u_mask[base]; }
    }
  }
  __syncthreads();

  // G1: g[16x512] = feat[16x128] @ A (+gc) -> sGWS f16
  {
    half8 a[4];
    #pragma unroll
    for (int kk = 0; kk < 4; kk++)
      a[kk] = ldh8(&sOP2[col*392 + 256 + kk*32 + chunk*8]);
    f32x4 acc[8];
    #pragma unroll
    for (int t = 0; t < 8; t++) acc[t] = (f32x4){0.f,0.f,0.f,0.f};
    const ushort* BP = wsu + APKo + (long)l*65536;
    #pragma unroll
    for (int t = 0; t < 8; t++) {
      int nt = wv*8 + t;
      #pragma unroll
      for (int kk = 0; kk < 4; kk++) {
        half8 b = ldh8(&BP[((nt*4+kk)*64 + lane)*8]);
        acc[t] = __builtin_amdgcn_mfma_f32_16x16x32_f16(a[kk], b, acc[t], 0, 0, 0);
      }
    }
    #pragma unroll
    for (int t = 0; t < 8; t++) {
      int N = (wv*8+t)*16 + col;
      float gcv = wsf[OFF_GC + l*512 + N];
      #pragma unroll
      for (int r = 0; r < 4; r++)
        sGWS[(chunk*4+r)*520 + N] = cvth(acc[t][r] + gcv);
    }
  }
  if (tid < 32) {   // qb[n][h]
    int n = tid >> 1, h = tid & 1;
    float s = wsf[OFF_CC + l*2 + h];
    const float* u = wsf + OFF_U + (l*2+h)*128;
    for (int i = 0; i < 128; i++) s += h2f(sOP2[n*392 + 256 + i])*u[i];
    sQB[tid] = s;
  }
  __syncthreads();

  // Phase A: 320 scores. Pass1: 256 items 1:1; Pass2: 64 items split 4 lanes each.
  {
    auto scorePart = [&](int p, int c0, int c1, float& r0, float& r1) {
      int n = p / K;
      float dtf = (float)(imem[16+n] - nbm[320+p]);
      const __half2* gp2 = (const __half2*)&sGWS[n*520];
      __half2 z = __floats2half2_rn(0.f, 0.f);
      __half2 A0 = z, B0 = z, A1 = z, B1 = z;
      if constexpr (NBF16) {
        const __half2* fr2 = (const __half2*)(nbu + (long)nbm[p]*D);
        for (int c = c0; c < c1; c++) {
          __half2 f0 = fr2[c*4+0], f1 = fr2[c*4+1];
          __half2 f2 = fr2[c*4+2], f3 = fr2[c*4+3];
          A0 = __hfma2(f0, gp2[c*4+0], A0);     B0 = __hfma2(f1, gp2[c*4+1], B0);
          A0 = __hfma2(f2, gp2[c*4+2], A0);     B0 = __hfma2(f3, gp2[c*4+3], B0);
          A1 = __hfma2(f0, gp2[128+c*4+0], A1); B1 = __hfma2(f1, gp2[128+c*4+1], B1);
          A1 = __hfma2(f2, gp2[128+c*4+2], A1); B1 = __hfma2(f3, gp2[128+c*4+3], B1);
        }
      } else {
        const float* fr = nbf + (long)nbm[p]*D;
        for (int c = c0; c < c1; c++) {
          __half2 f0 = __floats2half2_rn(fr[c*8+0], fr[c*8+1]);
          __half2 f1 = __floats2half2_rn(fr[c*8+2], fr[c*8+3]);
          __half2 f2 = __floats2half2_rn(fr[c*8+4], fr[c*8+5]);
          __half2 f3 = __floats2half2_rn(fr[c*8+6], fr[c*8+7]);
          A0 = __hfma2(f0, gp2[c*4+0], A0);     B0 = __hfma2(f1, gp2[c*4+1], B0);
          A0 = __hfma2(f2, gp2[c*4+2], A0);     B0 = __hfma2(f3, gp2[c*4+3], B0);
          A1 = __hfma2(f0, gp2[128+c*4+0], A1); B1 = __hfma2(f1, gp2[128+c*4+1], B1);
          A1 = __hfma2(f2, gp2[128+c*4+2], A1); B1 = __hfma2(f3, gp2[128+c*4+3], B1);
        }
      }
      for (int c = c0; c < c1; c++) {
        int j = c*8;
        __half2 cA = __floats2half2_rn(
            cosr(__fadd_rn(__fmul_rn(dtf, sTW[j+0]), sTB[j+0])),
            cosr(__fadd_rn(__fmul_rn(dtf, sTW[j+1]), sTB[j+1])));
        __half2 cB = __floats2half2_rn(
            cosr(__fadd_rn(__fmul_rn(dtf, sTW[j+2]), sTB[j+2])),
            cosr(__fadd_rn(__fmul_rn(dtf, sTW[j+3]), sTB[j+3])));
        __half2 cC = __floats2half2_rn(
            cosr(__fadd_rn(__fmul_rn(dtf, sTW[j+4]), sTB[j+4])),
            cosr(__fadd_rn(__fmul_rn(dtf, sTW[j+5]), sTB[j+5])));
        __half2 cD = __floats2half2_rn(
            cosr(__fadd_rn(__fmul_rn(dtf, sTW[j+6]), sTB[j+6])),
            cosr(__fadd_rn(__fmul_rn(dtf, sTW[j+7]), sTB[j+7])));
        A0 = __hfma2(cA, gp2[64+c*4+0], A0);     B0 = __hfma2(cB, gp2[64+c*4+1], B0);
        A0 = __hfma2(cC, gp2[64+c*4+2], A0);     B0 = __hfma2(cD, gp2[64+c*4+3], B0);
        A1 = __hfma2(cA, gp2[192+c*4+0], A1);    B1 = __hfma2(cB, gp2[192+c*4+1], B1);
        A1 = __hfma2(cC, gp2[192+c*4+2], A1);    B1 = __hfma2(cD, gp2[192+c*4+3], B1);
      }
      __half2 S0 = __hadd2(A0, B0), S1 = __hadd2(A1, B1);
      r0 = __low2float(S0) + __high2float(S0);
      r1 = __low2float(S1) + __high2float(S1);
    };
    const float invsq = 0.08838834764831845f;
    {   // pass 1: items 0..255
      int p = tid;
      float a0, a1;
      scorePart(p, 0, 16, a0, a1);
      int n = p / K, k = p - n*K;
      int m = nbm[640+p];
      sAL[n*40 + k]      = m > 0 ? (a0 + sQB[n*2])*invsq   : -1e9f;
      sAL[n*40 + 20 + k] = m > 0 ? (a1 + sQB[n*2+1])*invsq : -1e9f;
    }
    {   // pass 2: items 256..319, 4 lanes per item
      int p = 256 + (tid >> 2), sub = tid & 3;
      float a0, a1;
      scorePart(p, sub*4, sub*4+4, a0, a1);
      a0 += __shfl_xor(a0, 1); a0 += __shfl_xor(a0, 2);
      a1 += __shfl_xor(a1, 1); a1 += __shfl_xor(a1, 2);
      if (sub == 0) {
        int n = p / K, k = p - n*K;
        int m = nbm[640+p];
        sAL[n*40 + k]      = m > 0 ? (a0 + sQB[n*2])*invsq   : -1e9f;
        sAL[n*40 + 20 + k] = m > 0 ? (a1 + sQB[n*2+1])*invsq : -1e9f;
      }
    }
  }
  __syncthreads();

  // softmax (+ f16 copy of weights)
  if (tid < 2*G) {
    int n = tid >> 1, h = tid & 1;
    float* a = &sAL[n*40 + h*20];
    ushort* ah = &sALh[n*40 + h*20];
    float mx = -1e30f;
    for (int k = 0; k < K; k++) mx = fmaxf(mx, a[k]);
    float s = 0.f;
    for (int k = 0; k < K; k++) { float e = __expf(a[k]-mx); a[k] = e; s += e; }
    float inv = 1.f/s;
    for (int k = 0; k < K; k++) { a[k] *= inv; ah[k] = cvth(a[k]); }
    if (h == 0) { int any = 0;
      for (int k = 0; k < K; k++) any |= nbm[640 + n*20 + k];
      imem[64+n] = any; }
  }
  __syncthreads();

  // Phase C: wsum -> sGWS f16; thread owns 8 contiguous dims; packed half2 accum
  {
    const int n = tid >> 4, e0 = tid & 15;
    const __half* alh = (const __half*)&sALh[n*40];
    __half2 z = __floats2half2_rn(0.f, 0.f);
    __half2 W0[4], W1[4];
    #pragma unroll
    for (int i = 0; i < 4; i++) { W0[i] = z; W1[i] = z; }
    #pragma unroll 4
    for (int k = 0; k < K; k++) {
      __half2 a0h = __half2half2(alh[k]);
      __half2 a1h = __half2half2(alh[20 + k]);
      if constexpr (NBF16) {
        const __half2* f2 = (const __half2*)(nbu + (long)nbm[n*20+k]*D + e0*8);
        #pragma unroll
        for (int i = 0; i < 4; i++) {
          __half2 f = f2[i];
          W0[i] = __hfma2(a0h, f, W0[i]);
          W1[i] = __hfma2(a1h, f, W1[i]);
        }
      } else {
        const float* fr = nbf + (long)nbm[n*20+k]*D + e0*8;
        #pragma unroll
        for (int i = 0; i < 4; i++) {
          __half2 f = __floats2half2_rn(fr[2*i], fr[2*i+1]);
          W0[i] = __hfma2(a0h, f, W0[i]);
          W1[i] = __hfma2(a1h, f, W1[i]);
        }
      }
    }
    #pragma unroll
    for (int i = 0; i < 4; i++) {
      *(__half2*)&sGWS[n*520 + e0*8 + 2*i]       = W0[i];
      *(__half2*)&sGWS[n*520 + 256 + e0*8 + 2*i] = W1[i];
    }
    // time part
    #pragma unroll
    for (int i = 0; i < 4; i++) { W0[i] = z; W1[i] = z; }
    float twv[8], tbv[8];
    #pragma unroll
    for (int i = 0; i < 8; i++) { twv[i] = sTW[e0*8+i]; tbv[i] = sTB[e0*8+i]; }
    for (int k = 0; k < K; k++) {
      __half2 a0h = __half2half2(alh[k]);
      __half2 a1h = __half2half2(alh[20 + k]);
      float dtf = (float)(imem[16+n] - nbm[320 + n*20 + k]);
      #pragma unroll
      for (int i = 0; i < 4; i++) {
        __half2 c2 = __floats2half2_rn(
            cosr(__fadd_rn(__fmul_rn(dtf, twv[2*i]),   tbv[2*i])),
            cosr(__fadd_rn(__fmul_rn(dtf, twv[2*i+1]), tbv[2*i+1])));
        W0[i] = __hfma2(a0h, c2, W0[i]);
        W1[i] = __hfma2(a1h, c2, W1[i]);
      }
    }
    #pragma unroll
    for (int i = 0; i < 4; i++) {
      *(__half2*)&sGWS[n*520 + 128 + e0*8 + 2*i] = W0[i];
      *(__half2*)&sGWS[n*520 + 384 + e0*8 + 2*i] = W1[i];
    }
  }
  __syncthreads();

  // G2: o = wsum_h @ Wv_h (+bv) -> sOP1
  {
    int h = wv >> 1, ntb = (wv & 1)*4;
    half8 a[8];
    #pragma unroll
    for (int kk = 0; kk < 8; kk++)
      a[kk] = ldh8(&sGWS[col*520 + h*256 + kk*32 + chunk*8]);
    f32x4 acc[4];
    #pragma unroll
    for (int t = 0; t < 4; t++) acc[t] = (f32x4){0.f,0.f,0.f,0.f};
    const ushort* BP = wsu + VPKo + (long)(l*2+h)*32768;
    #pragma unroll
    for (int t = 0; t < 4; t++) {
      int nt = ntb + t;
      #pragma unroll
      for (int kk = 0; kk < 8; kk++) {
        half8 b = ldh8(&BP[((nt*8+kk)*64 + lane)*8]);
        acc[t] = __builtin_amdgcn_mfma_f32_16x16x32_f16(a[kk], b, acc[t], 0, 0, 0);
      }
    }
    #pragma unroll
    for (int t = 0; t < 4; t++) {
      int ocol = h*128 + (ntb+t)*16 + col;
      float bb = bv[l*256 + ocol];
      #pragma unroll
      for (int r = 0; r < 4; r++)
        sOP1[(chunk*4+r)*264 + ocol] = cvth(acc[t][r] + bb);
    }
  }
  __syncthreads();

  // G3: oo = o @ Wo (+bo, anyv mask) -> sOP2 cols 0..255
  {
    half8 a[8];
    #pragma unroll
    for (int kk = 0; kk < 8; kk++)
      a[kk] = ldh8(&sOP1[col*264 + kk*32 + chunk*8]);
    f32x4 acc[4];
    #pragma unroll
    for (int t = 0; t < 4; t++) acc[t] = (f32x4){0.f,0.f,0.f,0.f};
    const ushort* BP = wsu + OPKo + (long)l*65536;
    #pragma unroll
    for (int t = 0; t < 4; t++) {
      int nt = wv*4 + t;
      #pragma unroll
      for (int kk = 0; kk < 8; kk++) {
        half8 b = ldh8(&BP[((nt*8+kk)*64 + lane)*8]);
        acc[t] = __builtin_amdgcn_mfma_f32_16x16x32_f16(a[kk], b, acc[t], 0, 0, 0);
      }
    }
    #pragma unroll
    for (int t = 0; t < 4; t++) {
      int e = (wv*4+t)*16 + col;
      float bb = bo[l*256 + e];
      #pragma unroll
      for (int r = 0; r < 4; r++) {
        int row = chunk*4 + r;
        float v = imem[64+row] ? (acc[t][r] + bb) : 0.f;
        sOP2[row*392 + e] = cvth(v);
      }
    }
  }
  __syncthreads();

  // G4: h1 = [oo,feat] @ W1 (+b1, relu) -> sOP1 cols 0..127
  {
    half8 a[12];
    #pragma unroll
    for (int kk = 0; kk < 12; kk++)
      a[kk] = ldh8(&sOP2[col*392 + kk*32 + chunk*8]);
    f32x4 acc[2];
    acc[0] = (f32x4){0.f,0.f,0.f,0.f}; acc[1] = (f32x4){0.f,0.f,0.f,0.f};
    const ushort* BP = wsu + W1PKo + (long)l*49152;
    #pragma unroll
    for (int t = 0; t < 2; t++) {
      int nt = wv*2 + t;
      #pragma unroll
      for (int kk = 0; kk < 12; kk++) {
        half8 b = ldh8(&BP[((nt*12+kk)*64 + lane)*8]);
        acc[t] = __builtin_amdgcn_mfma_f32_16x16x32_f16(a[kk], b, acc[t], 0, 0, 0);
      }
    }
    #pragma unroll
    for (int t = 0; t < 2; t++) {
      int dcol = (wv*2+t)*16 + col;
      float bb = b1[l*128 + dcol];
      #pragma unroll
      for (int r = 0; r < 4; r++)
        sOP1[(chunk*4+r)*264 + dcol] = cvth(fmaxf(acc[t][r] + bb, 0.f));
    }
  }
  __syncthreads();

  // G5: out = h1 @ W2 (+b2) -> NBR f16 (L0) or global f32 (L1)
  {
    half8 a[4];
    #pragma unroll
    for (int kk = 0; kk < 4; kk++)
      a[kk] = ldh8(&sOP1[col*264 + kk*32 + chunk*8]);
    f32x4 acc[2];
    acc[0] = (f32x4){0.f,0.f,0.f,0.f}; acc[1] = (f32x4){0.f,0.f,0.f,0.f};
    const ushort* BP = wsu + W2PKo + (long)l*16384;
    #pragma unroll
    for (int t = 0; t < 2; t++) {
      int nt = wv*2 + t;
      #pragma unroll
      for (int kk = 0; kk < 4; kk++) {
        half8 b = ldh8(&BP[((nt*4+kk)*64 + lane)*8]);
        acc[t] = __builtin_amdgcn_mfma_f32_16x16x32_f16(a[kk], b, acc[t], 0, 0, 0);
      }
    }
    #pragma unroll
    for (int t = 0; t < 2; t++) {
      int dcol = (wv*2+t)*16 + col;
      float bb = b2[l*128 + dcol];
      #pragma unroll
      for (int r = 0; r < 4; r++) {
        int row = chunk*4 + r;
        float v = acc[t][r] + bb;
        if (LAYER == 0) { if (imem[80+row]) nbrOut[(long)imem[48+row]*D + dcol] = cvth(v); }
        else            out[(long)(blk*G + row)*D + dcol] = v;
      }
    }
  }
}

extern "C" void kernel_launch(void* const* d_in, const int* in_sizes, int n_in,
                              void* d_out, int out_size, void* d_ws, size_t ws_size,
                              hipStream_t stream) {
  const int* nodes  = (const int*)d_in[0];
  const int* edges  = (const int*)d_in[1];
  const int* tst    = (const int*)d_in[2];
  const int* u_neig = (const int*)d_in[4];
  const int* u_edges= (const int*)d_in[5];
  const int* u_times= (const int*)d_in[6];
  const int* u_mask = (const int*)d_in[7];
  const int* i_neig = (const int*)d_in[8];
  const int* i_times= (const int*)d_in[10];
  const int* i_mask = (const int*)d_in[11];
  const float* user_emb = (const float*)d_in[12];
  const float* item_emb = (const float*)d_in[13];
  const float* time_w = (const float*)d_in[14];
  const float* time_b = (const float*)d_in[15];
  const float* Wq = (const float*)d_in[16]; const float* bq = (const float*)d_in[17];
  const float* Wk = (const float*)d_in[18]; const float* bk = (const float*)d_in[19];
  const float* Wv = (const float*)d_in[20]; const float* bv = (const float*)d_in[21];
  const float* Wo = (const float*)d_in[22]; const float* bo = (const float*)d_in[23];
  const float* W1 = (const float*)d_in[24]; const float* b1 = (const float*)d_in[25];
  const float* W2 = (const float*)d_in[26]; const float* b2 = (const float*)d_in[27];
  float* ws = (float*)d_ws;
  float* out = (float*)d_out;

  bool emb16 = ws_size >= (size_t)WS_NEED_F * 4;

  prep<<<dim3(emb16 ? 8302 : 2052), dim3(256), 0, stream>>>(
      Wq, Wk, bq, bk, time_b, Wv, Wo, W1, W2, user_emb, ws);
  compact_valid<<<dim3(160), dim3(256), 0, stream>>>(edges, u_mask, ws);

  if (emb16)
    attend<0,true><<<dim3(NSLOT/G), dim3(256), 0, stream>>>(
        nodes, edges, tst, u_edges, u_neig, u_times, u_mask,
        i_neig, i_times, i_mask, user_emb, item_emb, time_w, time_b,
        bv, bo, b1, b2, ws, out);
  else
    attend<0,false><<<dim3(NSLOT/G), dim3(256), 0, stream>>>(
        nodes, edges, tst, u_edges, u_neig, u_times, u_mask,
        i_neig, i_times, i_mask, user_emb, item_emb, time_w, time_b,
        bv, bo, b1, b2, ws, out);

  attend<1,true><<<dim3(NB_B/G), dim3(256), 0, stream>>>(
      nodes, edges, tst, u_edges, u_neig, u_times, u_mask,
      i_neig, i_times, i_mask, user_emb, item_emb, time_w, time_b,
      bv, bo, b1, b2, ws, out);
}

// Round 14
// 132.023 us; speedup vs baseline: 1.8339x; 1.0457x over previous
//
#include <hip/hip_runtime.h>
#include <hip/hip_bf16.h>
#include <hip/hip_fp16.h>

#define TBL 50
#define K 20
#define D 128
#define E 256
#define NB_B 2048
#define NSLOT (NB_B*K)     // 40960
#define G 16

typedef unsigned short ushort;
typedef unsigned short ushort8 __attribute__((ext_vector_type(8)));
typedef float f32x4 __attribute__((ext_vector_type(4)));
typedef _Float16 half8 __attribute__((ext_vector_type(8)));

// ws float offsets
#define OFF_GC    0              // [l2][512] f32
#define OFF_U     1024           // [l2*2][128] f32
#define OFF_CC    1536           // [4] f32
#define OFF_PKF   2052           // packed f16 weights (524288 ushorts)
#define OFF_NBRB  264196         // NBR f16 [40960][128] ushorts
#define OFF_CNT   2885636        // int count; int compact[40960]
#define OFF_UEB   2926600        // user_emb f16 [100000][128] ushorts
#define WS_NEED_F (OFF_UEB + 6400000)
// ushort offsets inside PK region
#define APKo   0
#define VPKo   131072
#define OPKo   262144
#define W1PKo  393216
#define W2PKo  491520

#define INV2PI 0.15915494309189535f

__device__ __forceinline__ float cosr(float x) {   // accurate path (prep only)
  const float HI = 0.15915493667125702f;
  const float LO = 6.4206383e-9f;
  float k = rintf(x * HI);
  float f = __fmaf_rn(x, HI, -k);
  f = __fmaf_rn(x, LO, f);
  return __builtin_amdgcn_cosf(f);
}
// fast: arg already in revolutions (w,b pre-scaled by 1/2pi); 3 inst total
__device__ __forceinline__ float cosq(float dtf, float w2, float b2) {
  float t = __fmaf_rn(dtf, w2, b2);
  return __builtin_amdgcn_cosf(__builtin_amdgcn_fractf(t));
}
__device__ __forceinline__ ushort cvth(float f) {
  union { _Float16 h; ushort u; } c; c.h = (_Float16)f; return c.u;
}
__device__ __forceinline__ float h2f(ushort u) {
  union { ushort u; _Float16 h; } c; c.u = u; return (float)c.h;
}
__device__ __forceinline__ half8 ldh8(const ushort* p) {
  union { ushort8 u; half8 h; } c;
  c.u = *(const ushort8*)p;
  return c.h;
}

// Fused preprocessing: blocks [0,516) = A/gc/u/cc; [516,2052) = weight pack;
// [2052,8302) = user_emb f16 pack.
__global__ __launch_bounds__(256) void prep(
    const float* __restrict__ Wq, const float* __restrict__ Wk,
    const float* __restrict__ bq, const float* __restrict__ bk,
    const float* __restrict__ time_b,
    const float* __restrict__ Wv, const float* __restrict__ Wo,
    const float* __restrict__ W1, const float* __restrict__ W2,
    const float* __restrict__ user_emb, float* __restrict__ ws)
{
  __shared__ float sqc[128], ctb[128];
  int b = blockIdx.x, t = threadIdx.x;
  ushort* wsu = (ushort*)(ws + OFF_PKF);
  if (b < 512) {           // A[l][h][i][j] -> APK f16
    int l = b >> 8, h = (b >> 7) & 1, i = b & 127;
    float s = 0.f;
    const float* wq = Wq + l*65536 + h*32768 + i;
    const float* wk = Wk + l*65536 + h*32768 + t;
    for (int m = 0; m < 128; m++) s += wq[m*256]*wk[m*256];
    int N = h*256 + t;
    int nt = N >> 4, cl = N & 15;
    int kk = i >> 5, ch = (i >> 3) & 3, bb = i & 7;
    wsu[APKo + (long)l*65536 + (((nt*4+kk)*64 + ch*16 + cl)*8) + bb] = cvth(s);
  } else if (b < 516) {
    int q = b - 512, l = q >> 1, h = q & 1;
    if (t < 128) ctb[t] = cosf(time_b[t]);
    __syncthreads();
    if (t < 128) {
      int e = h*128 + t;
      float a = bq[l*256 + e];
      const float* wq = Wq + l*65536 + e*256 + 128;
      for (int m = 0; m < 128; m++) a += wq[m]*ctb[m];
      sqc[t] = a;
    }
    __syncthreads();
    { float s = 0.f;      // gc
      const float* wk = Wk + l*65536 + h*32768 + t;
      for (int m = 0; m < 128; m++) s += sqc[m]*wk[m*256];
      ws[OFF_GC + l*512 + h*256 + t] = s; }
    if (t < 128) {        // u
      float s = 0.f;
      const float* wq = Wq + l*65536 + h*32768 + t;
      const float* bkp = bk + l*256 + h*128;
      for (int m = 0; m < 128; m++) s += wq[m*256]*bkp[m];
      ws[OFF_U + (l*2+h)*128 + t] = s; }
    if (t == 254) {       // cc
      float s = 0.f;
      const float* bkp = bk + l*256 + h*128;
      for (int m = 0; m < 128; m++) s += sqc[m]*bkp[m];
      ws[OFF_CC + l*2+h] = s; }
  } else if (b < 2052) {   // weight pack
    int idx = (b - 516)*256 + t;   // < 393216
    if (idx == 0) *(int*)(ws + OFF_CNT) = 0;
    if (idx < 131072) {          // VPK
      int q = idx >> 15, r = idx & 32767, l = q >> 1, h = q & 1;
      int bb = r & 7, lane = (r >> 3) & 63, kk = (r >> 9) & 7, nt = r >> 12;
      int k = kk*32 + (lane>>4)*8 + bb, d = nt*16 + (lane&15);
      wsu[VPKo + idx] = cvth(Wv[l*65536 + (h*128+d)*256 + k]);
    } else if (idx < 262144) {   // OPK
      int rel = idx - 131072, l = rel >> 16, r = rel & 65535;
      int bb = r & 7, lane = (r >> 3) & 63, kk = (r >> 9) & 7, nt = r >> 12;
      int k = kk*32 + (lane>>4)*8 + bb, e = nt*16 + (lane&15);
      wsu[OPKo + rel] = cvth(Wo[l*65536 + e*256 + k]);
    } else if (idx < 360448) {   // W1PK
      int rel = idx - 262144, l = rel / 49152, r = rel % 49152;
      int nt = r / 6144, rr = r - nt*6144;
      int kk = rr >> 9, lane = (rr >> 3) & 63, bb = rr & 7;
      int k = kk*32 + (lane>>4)*8 + bb, d = nt*16 + (lane&15);
      wsu[W1PKo + rel] = cvth(W1[l*49152 + d*384 + k]);
    } else {                     // W2PK
      int rel = idx - 360448, l = rel >> 14, r = rel & 16383;
      int nt = r >> 11, rr = r & 2047;
      int kk = rr >> 9, lane = (rr >> 3) & 63, bb = rr & 7;
      int k = kk*32 + (lane>>4)*8 + bb, d = nt*16 + (lane&15);
      wsu[W2PKo + rel] = cvth(W2[l*16384 + d*128 + k]);
    }
  } else {                 // user_emb pack
    int idx = (b - 2052)*256 + t;  // < 1600000
    float4 a = ((const float4*)user_emb)[idx*2];
    float4 bb = ((const float4*)user_emb)[idx*2+1];
    ushort8 o;
    o[0]=cvth(a.x); o[1]=cvth(a.y); o[2]=cvth(a.z); o[3]=cvth(a.w);
    o[4]=cvth(bb.x); o[5]=cvth(bb.y); o[6]=cvth(bb.z); o[7]=cvth(bb.w);
    ((ushort8*)(ws + OFF_UEB))[idx] = o;
  }
}

__global__ __launch_bounds__(256) void compact_valid(
    const int* __restrict__ edges, const int* __restrict__ u_mask,
    float* __restrict__ ws)
{
  int idx = blockIdx.x*256 + threadIdx.x;    // < 40960
  int b = idx / K, s = idx - b*K;
  int pe = edges[b];
  if (u_mask[pe*TBL + (TBL-K) + s] > 0) {
    int pos = atomicAdd((int*)(ws + OFF_CNT), 1);
    ((int*)(ws + OFF_CNT))[1 + pos] = idx;
  }
}

template<int LAYER, bool NBF16>
__global__ __launch_bounds__(256, 3) void attend(
    const int* __restrict__ nodes, const int* __restrict__ edges, const int* __restrict__ tstamps,
    const int* __restrict__ u_edges, const int* __restrict__ u_neig,
    const int* __restrict__ u_times, const int* __restrict__ u_mask,
    const int* __restrict__ i_neig, const int* __restrict__ i_times, const int* __restrict__ i_mask,
    const float* __restrict__ user_emb, const float* __restrict__ item_emb,
    const float* __restrict__ time_w, const float* __restrict__ time_b,
    const float* __restrict__ bv, const float* __restrict__ bo,
    const float* __restrict__ b1, const float* __restrict__ b2,
    float* __restrict__ wsf, float* __restrict__ out)
{
  __shared__ __align__(16) ushort sOP2[16*392];  // [oo(256) | feat(128) | pad]  (f16)
  __shared__ __align__(16) ushort sGWS[16*520];  // g then wsum (f16)
  __shared__ __align__(16) ushort sOP1[16*264];  // o then h1 (f16)
  __shared__ float sTW[128], sTB[128], sAL[640], sQB[32];   // sTW/sTB pre-scaled by 1/2pi
  __shared__ ushort sALh[640];                   // f16 copy of softmax weights
  __shared__ int imem[96];
  __shared__ int nbm[960];

  const int tid = threadIdx.x, blk = blockIdx.x, l = LAYER;
  const int lane = tid & 63, wv = tid >> 6;
  const int col = lane & 15, chunk = lane >> 4;
  const ushort* wsu = (const ushort*)(wsf + OFF_PKF);
  const ushort* nbu = NBF16 ? ((LAYER == 0) ? (const ushort*)(wsf + OFF_UEB)
                                            : (const ushort*)(wsf + OFF_NBRB))
                            : (const ushort*)nullptr;
  const float*  nbf = user_emb;  // f32 fallback (LAYER==0 only)
  ushort* nbrOut = (ushort*)(wsf + OFF_NBRB);

  int count = (LAYER == 0) ? *(const int*)(wsf + OFF_CNT) : NB_B;
  if (blk*G >= count) return;

  if (tid < G) {
    int idx = blk*G + tid; int act = idx < count ? 1 : 0;
    int slot, nid, ntm, erow;
    if (LAYER == 0) {
      int ii = act ? idx : 0;
      slot = ((const int*)(wsf + OFF_CNT))[1 + ii];
      int bb = slot / K, s = slot - bb*K;
      int base = edges[bb]*TBL + (TBL-K) + s;
      nid = u_neig[base]; ntm = u_times[base]; erow = u_edges[base];
    } else { slot = idx; nid = nodes[idx]; ntm = tstamps[idx]; erow = edges[idx]; }
    imem[tid] = nid; imem[16+tid] = ntm; imem[32+tid] = erow;
    imem[48+tid] = slot; imem[80+tid] = act;
  }
  if (tid < 128) { sTW[tid] = time_w[tid] * INV2PI; sTB[tid] = time_b[tid] * INV2PI; }
  __syncthreads();

  // P0: gather feat -> OP2 cols 256..383 (f16); neighbor meta
  const float* nemb = (LAYER == 0) ? item_emb : user_emb;
  #pragma unroll
  for (int it = 0; it < 8; it++) {
    int idx = tid + it*256, n = idx >> 7, i = idx & 127;
    sOP2[n*392 + 256 + i] = cvth(nemb[(long)imem[n]*D + i]);
  }
  #pragma unroll
  for (int it = 0; it < 2; it++) {
    int p = tid + it*256;
    if (p < G*K) {
      int n = p / K, k = p - n*K;
      int base = imem[32+n]*TBL + (TBL-K) + k;
      if (LAYER == 0) { nbm[p] = i_neig[base]; nbm[320+p] = i_times[base]; nbm[640+p] = i_mask[base]; }
      else            { nbm[p] = (blk*G+n)*K + k; nbm[320+p] = u_times[base]; nbm[640+p] = u_mask[base]; }
    }
  }
  __syncthreads();

  // G1: g[16x512] = feat[16x128] @ A (+gc) -> sGWS f16
  {
    half8 a[4];
    #pragma unroll
    for (int kk = 0; kk < 4; kk++)
      a[kk] = ldh8(&sOP2[col*392 + 256 + kk*32 + chunk*8]);
    f32x4 acc[8];
    #pragma unroll
    for (int t = 0; t < 8; t++) acc[t] = (f32x4){0.f,0.f,0.f,0.f};
    const ushort* BP = wsu + APKo + (long)l*65536;
    #pragma unroll
    for (int t = 0; t < 8; t++) {
      int nt = wv*8 + t;
      #pragma unroll
      for (int kk = 0; kk < 4; kk++) {
        half8 b = ldh8(&BP[((nt*4+kk)*64 + lane)*8]);
        acc[t] = __builtin_amdgcn_mfma_f32_16x16x32_f16(a[kk], b, acc[t], 0, 0, 0);
      }
    }
    #pragma unroll
    for (int t = 0; t < 8; t++) {
      int N = (wv*8+t)*16 + col;
      float gcv = wsf[OFF_GC + l*512 + N];
      #pragma unroll
      for (int r = 0; r < 4; r++)
        sGWS[(chunk*4+r)*520 + N] = cvth(acc[t][r] + gcv);
    }
  }
  if (tid < 32) {   // qb[n][h]
    int n = tid >> 1, h = tid & 1;
    float s = wsf[OFF_CC + l*2 + h];
    const float* u = wsf + OFF_U + (l*2+h)*128;
    for (int i = 0; i < 128; i++) s += h2f(sOP2[n*392 + 256 + i])*u[i];
    sQB[tid] = s;
  }
  __syncthreads();

  // Phase A: 320 scores. Pass1: 256 items 1:1; Pass2: 64 items split 4 lanes each.
  {
    auto scorePart = [&](int p, int c0, int c1, float& r0, float& r1) {
      int n = p / K;
      float dtf = (float)(imem[16+n] - nbm[320+p]);
      const __half2* gp2 = (const __half2*)&sGWS[n*520];
      __half2 z = __floats2half2_rn(0.f, 0.f);
      __half2 A0 = z, B0 = z, A1 = z, B1 = z;
      if constexpr (NBF16) {
        const __half2* fr2 = (const __half2*)(nbu + (long)nbm[p]*D);
        for (int c = c0; c < c1; c++) {
          __half2 f0 = fr2[c*4+0], f1 = fr2[c*4+1];
          __half2 f2 = fr2[c*4+2], f3 = fr2[c*4+3];
          A0 = __hfma2(f0, gp2[c*4+0], A0);     B0 = __hfma2(f1, gp2[c*4+1], B0);
          A0 = __hfma2(f2, gp2[c*4+2], A0);     B0 = __hfma2(f3, gp2[c*4+3], B0);
          A1 = __hfma2(f0, gp2[128+c*4+0], A1); B1 = __hfma2(f1, gp2[128+c*4+1], B1);
          A1 = __hfma2(f2, gp2[128+c*4+2], A1); B1 = __hfma2(f3, gp2[128+c*4+3], B1);
        }
      } else {
        const float* fr = nbf + (long)nbm[p]*D;
        for (int c = c0; c < c1; c++) {
          __half2 f0 = __floats2half2_rn(fr[c*8+0], fr[c*8+1]);
          __half2 f1 = __floats2half2_rn(fr[c*8+2], fr[c*8+3]);
          __half2 f2 = __floats2half2_rn(fr[c*8+4], fr[c*8+5]);
          __half2 f3 = __floats2half2_rn(fr[c*8+6], fr[c*8+7]);
          A0 = __hfma2(f0, gp2[c*4+0], A0);     B0 = __hfma2(f1, gp2[c*4+1], B0);
          A0 = __hfma2(f2, gp2[c*4+2], A0);     B0 = __hfma2(f3, gp2[c*4+3], B0);
          A1 = __hfma2(f0, gp2[128+c*4+0], A1); B1 = __hfma2(f1, gp2[128+c*4+1], B1);
          A1 = __hfma2(f2, gp2[128+c*4+2], A1); B1 = __hfma2(f3, gp2[128+c*4+3], B1);
        }
      }
      for (int c = c0; c < c1; c++) {
        int j = c*8;
        __half2 cA = __floats2half2_rn(cosq(dtf, sTW[j+0], sTB[j+0]),
                                       cosq(dtf, sTW[j+1], sTB[j+1]));
        __half2 cB = __floats2half2_rn(cosq(dtf, sTW[j+2], sTB[j+2]),
                                       cosq(dtf, sTW[j+3], sTB[j+3]));
        __half2 cC = __floats2half2_rn(cosq(dtf, sTW[j+4], sTB[j+4]),
                                       cosq(dtf, sTW[j+5], sTB[j+5]));
        __half2 cD = __floats2half2_rn(cosq(dtf, sTW[j+6], sTB[j+6]),
                                       cosq(dtf, sTW[j+7], sTB[j+7]));
        A0 = __hfma2(cA, gp2[64+c*4+0], A0);     B0 = __hfma2(cB, gp2[64+c*4+1], B0);
        A0 = __hfma2(cC, gp2[64+c*4+2], A0);     B0 = __hfma2(cD, gp2[64+c*4+3], B0);
        A1 = __hfma2(cA, gp2[192+c*4+0], A1);    B1 = __hfma2(cB, gp2[192+c*4+1], B1);
        A1 = __hfma2(cC, gp2[192+c*4+2], A1);    B1 = __hfma2(cD, gp2[192+c*4+3], B1);
      }
      __half2 S0 = __hadd2(A0, B0), S1 = __hadd2(A1, B1);
      r0 = __low2float(S0) + __high2float(S0);
      r1 = __low2float(S1) + __high2float(S1);
    };
    const float invsq = 0.08838834764831845f;
    {   // pass 1: items 0..255
      int p = tid;
      float a0, a1;
      scorePart(p, 0, 16, a0, a1);
      int n = p / K, k = p - n*K;
      int m = nbm[640+p];
      sAL[n*40 + k]      = m > 0 ? (a0 + sQB[n*2])*invsq   : -1e9f;
      sAL[n*40 + 20 + k] = m > 0 ? (a1 + sQB[n*2+1])*invsq : -1e9f;
    }
    {   // pass 2: items 256..319, 4 lanes per item
      int p = 256 + (tid >> 2), sub = tid & 3;
      float a0, a1;
      scorePart(p, sub*4, sub*4+4, a0, a1);
      a0 += __shfl_xor(a0, 1); a0 += __shfl_xor(a0, 2);
      a1 += __shfl_xor(a1, 1); a1 += __shfl_xor(a1, 2);
      if (sub == 0) {
        int n = p / K, k = p - n*K;
        int m = nbm[640+p];
        sAL[n*40 + k]      = m > 0 ? (a0 + sQB[n*2])*invsq   : -1e9f;
        sAL[n*40 + 20 + k] = m > 0 ? (a1 + sQB[n*2+1])*invsq : -1e9f;
      }
    }
  }
  __syncthreads();

  // softmax (+ f16 copy of weights)
  if (tid < 2*G) {
    int n = tid >> 1, h = tid & 1;
    float* a = &sAL[n*40 + h*20];
    ushort* ah = &sALh[n*40 + h*20];
    float mx = -1e30f;
    for (int k = 0; k < K; k++) mx = fmaxf(mx, a[k]);
    float s = 0.f;
    for (int k = 0; k < K; k++) { float e = __expf(a[k]-mx); a[k] = e; s += e; }
    float inv = 1.f/s;
    for (int k = 0; k < K; k++) { a[k] *= inv; ah[k] = cvth(a[k]); }
    if (h == 0) { int any = 0;
      for (int k = 0; k < K; k++) any |= nbm[640 + n*20 + k];
      imem[64+n] = any; }
  }
  __syncthreads();

  // Phase C: wsum -> sGWS f16; thread owns 8 contiguous dims; packed half2 accum
  {
    const int n = tid >> 4, e0 = tid & 15;
    const __half* alh = (const __half*)&sALh[n*40];
    __half2 z = __floats2half2_rn(0.f, 0.f);
    __half2 W0[4], W1[4];
    #pragma unroll
    for (int i = 0; i < 4; i++) { W0[i] = z; W1[i] = z; }
    #pragma unroll 4
    for (int k = 0; k < K; k++) {
      __half2 a0h = __half2half2(alh[k]);
      __half2 a1h = __half2half2(alh[20 + k]);
      if constexpr (NBF16) {
        const __half2* f2 = (const __half2*)(nbu + (long)nbm[n*20+k]*D + e0*8);
        #pragma unroll
        for (int i = 0; i < 4; i++) {
          __half2 f = f2[i];
          W0[i] = __hfma2(a0h, f, W0[i]);
          W1[i] = __hfma2(a1h, f, W1[i]);
        }
      } else {
        const float* fr = nbf + (long)nbm[n*20+k]*D + e0*8;
        #pragma unroll
        for (int i = 0; i < 4; i++) {
          __half2 f = __floats2half2_rn(fr[2*i], fr[2*i+1]);
          W0[i] = __hfma2(a0h, f, W0[i]);
          W1[i] = __hfma2(a1h, f, W1[i]);
        }
      }
    }
    #pragma unroll
    for (int i = 0; i < 4; i++) {
      *(__half2*)&sGWS[n*520 + e0*8 + 2*i]       = W0[i];
      *(__half2*)&sGWS[n*520 + 256 + e0*8 + 2*i] = W1[i];
    }
    // time part
    #pragma unroll
    for (int i = 0; i < 4; i++) { W0[i] = z; W1[i] = z; }
    float twv[8], tbv[8];
    #pragma unroll
    for (int i = 0; i < 8; i++) { twv[i] = sTW[e0*8+i]; tbv[i] = sTB[e0*8+i]; }
    for (int k = 0; k < K; k++) {
      __half2 a0h = __half2half2(alh[k]);
      __half2 a1h = __half2half2(alh[20 + k]);
      float dtf = (float)(imem[16+n] - nbm[320 + n*20 + k]);
      #pragma unroll
      for (int i = 0; i < 4; i++) {
        __half2 c2 = __floats2half2_rn(cosq(dtf, twv[2*i],   tbv[2*i]),
                                       cosq(dtf, twv[2*i+1], tbv[2*i+1]));
        W0[i] = __hfma2(a0h, c2, W0[i]);
        W1[i] = __hfma2(a1h, c2, W1[i]);
      }
    }
    #pragma unroll
    for (int i = 0; i < 4; i++) {
      *(__half2*)&sGWS[n*520 + 128 + e0*8 + 2*i] = W0[i];
      *(__half2*)&sGWS[n*520 + 384 + e0*8 + 2*i] = W1[i];
    }
  }
  __syncthreads();

  // G2: o = wsum_h @ Wv_h (+bv) -> sOP1
  {
    int h = wv >> 1, ntb = (wv & 1)*4;
    half8 a[8];
    #pragma unroll
    for (int kk = 0; kk < 8; kk++)
      a[kk] = ldh8(&sGWS[col*520 + h*256 + kk*32 + chunk*8]);
    f32x4 acc[4];
    #pragma unroll
    for (int t = 0; t < 4; t++) acc[t] = (f32x4){0.f,0.f,0.f,0.f};
    const ushort* BP = wsu + VPKo + (long)(l*2+h)*32768;
    #pragma unroll
    for (int t = 0; t < 4; t++) {
      int nt = ntb + t;
      #pragma unroll
      for (int kk = 0; kk < 8; kk++) {
        half8 b = ldh8(&BP[((nt*8+kk)*64 + lane)*8]);
        acc[t] = __builtin_amdgcn_mfma_f32_16x16x32_f16(a[kk], b, acc[t], 0, 0, 0);
      }
    }
    #pragma unroll
    for (int t = 0; t < 4; t++) {
      int ocol = h*128 + (ntb+t)*16 + col;
      float bb = bv[l*256 + ocol];
      #pragma unroll
      for (int r = 0; r < 4; r++)
        sOP1[(chunk*4+r)*264 + ocol] = cvth(acc[t][r] + bb);
    }
  }
  __syncthreads();

  // G3: oo = o @ Wo (+bo, anyv mask) -> sOP2 cols 0..255
  {
    half8 a[8];
    #pragma unroll
    for (int kk = 0; kk < 8; kk++)
      a[kk] = ldh8(&sOP1[col*264 + kk*32 + chunk*8]);
    f32x4 acc[4];
    #pragma unroll
    for (int t = 0; t < 4; t++) acc[t] = (f32x4){0.f,0.f,0.f,0.f};
    const ushort* BP = wsu + OPKo + (long)l*65536;
    #pragma unroll
    for (int t = 0; t < 4; t++) {
      int nt = wv*4 + t;
      #pragma unroll
      for (int kk = 0; kk < 8; kk++) {
        half8 b = ldh8(&BP[((nt*8+kk)*64 + lane)*8]);
        acc[t] = __builtin_amdgcn_mfma_f32_16x16x32_f16(a[kk], b, acc[t], 0, 0, 0);
      }
    }
    #pragma unroll
    for (int t = 0; t < 4; t++) {
      int e = (wv*4+t)*16 + col;
      float bb = bo[l*256 + e];
      #pragma unroll
      for (int r = 0; r < 4; r++) {
        int row = chunk*4 + r;
        float v = imem[64+row] ? (acc[t][r] + bb) : 0.f;
        sOP2[row*392 + e] = cvth(v);
      }
    }
  }
  __syncthreads();

  // G4: h1 = [oo,feat] @ W1 (+b1, relu) -> sOP1 cols 0..127
  {
    half8 a[12];
    #pragma unroll
    for (int kk = 0; kk < 12; kk++)
      a[kk] = ldh8(&sOP2[col*392 + kk*32 + chunk*8]);
    f32x4 acc[2];
    acc[0] = (f32x4){0.f,0.f,0.f,0.f}; acc[1] = (f32x4){0.f,0.f,0.f,0.f};
    const ushort* BP = wsu + W1PKo + (long)l*49152;
    #pragma unroll
    for (int t = 0; t < 2; t++) {
      int nt = wv*2 + t;
      #pragma unroll
      for (int kk = 0; kk < 12; kk++) {
        half8 b = ldh8(&BP[((nt*12+kk)*64 + lane)*8]);
        acc[t] = __builtin_amdgcn_mfma_f32_16x16x32_f16(a[kk], b, acc[t], 0, 0, 0);
      }
    }
    #pragma unroll
    for (int t = 0; t < 2; t++) {
      int dcol = (wv*2+t)*16 + col;
      float bb = b1[l*128 + dcol];
      #pragma unroll
      for (int r = 0; r < 4; r++)
        sOP1[(chunk*4+r)*264 + dcol] = cvth(fmaxf(acc[t][r] + bb, 0.f));
    }
  }
  __syncthreads();

  // G5: out = h1 @ W2 (+b2) -> NBR f16 (L0) or global f32 (L1)
  {
    half8 a[4];
    #pragma unroll
    for (int kk = 0; kk < 4; kk++)
      a[kk] = ldh8(&sOP1[col*264 + kk*32 + chunk*8]);
    f32x4 acc[2];
    acc[0] = (f32x4){0.f,0.f,0.f,0.f}; acc[1] = (f32x4){0.f,0.f,0.f,0.f};
    const ushort* BP = wsu + W2PKo + (long)l*16384;
    #pragma unroll
    for (int t = 0; t < 2; t++) {
      int nt = wv*2 + t;
      #pragma unroll
      for (int kk = 0; kk < 4; kk++) {
        half8 b = ldh8(&BP[((nt*4+kk)*64 + lane)*8]);
        acc[t] = __builtin_amdgcn_mfma_f32_16x16x32_f16(a[kk], b, acc[t], 0, 0, 0);
      }
    }
    #pragma unroll
    for (int t = 0; t < 2; t++) {
      int dcol = (wv*2+t)*16 + col;
      float bb = b2[l*128 + dcol];
      #pragma unroll
      for (int r = 0; r < 4; r++) {
        int row = chunk*4 + r;
        float v = acc[t][r] + bb;
        if (LAYER == 0) { if (imem[80+row]) nbrOut[(long)imem[48+row]*D + dcol] = cvth(v); }
        else            out[(long)(blk*G + row)*D + dcol] = v;
      }
    }
  }
}

extern "C" void kernel_launch(void* const* d_in, const int* in_sizes, int n_in,
                              void* d_out, int out_size, void* d_ws, size_t ws_size,
                              hipStream_t stream) {
  const int* nodes  = (const int*)d_in[0];
  const int* edges  = (const int*)d_in[1];
  const int* tst    = (const int*)d_in[2];
  const int* u_neig = (const int*)d_in[4];
  const int* u_edges= (const int*)d_in[5];
  const int* u_times= (const int*)d_in[6];
  const int* u_mask = (const int*)d_in[7];
  const int* i_neig = (const int*)d_in[8];
  const int* i_times= (const int*)d_in[10];
  const int* i_mask = (const int*)d_in[11];
  const float* user_emb = (const float*)d_in[12];
  const float* item_emb = (const float*)d_in[13];
  const float* time_w = (const float*)d_in[14];
  const float* time_b = (const float*)d_in[15];
  const float* Wq = (const float*)d_in[16]; const float* bq = (const float*)d_in[17];
  const float* Wk = (const float*)d_in[18]; const float* bk = (const float*)d_in[19];
  const float* Wv = (const float*)d_in[20]; const float* bv = (const float*)d_in[21];
  const float* Wo = (const float*)d_in[22]; const float* bo = (const float*)d_in[23];
  const float* W1 = (const float*)d_in[24]; const float* b1 = (const float*)d_in[25];
  const float* W2 = (const float*)d_in[26]; const float* b2 = (const float*)d_in[27];
  float* ws = (float*)d_ws;
  float* out = (float*)d_out;

  bool emb16 = ws_size >= (size_t)WS_NEED_F * 4;

  prep<<<dim3(emb16 ? 8302 : 2052), dim3(256), 0, stream>>>(
      Wq, Wk, bq, bk, time_b, Wv, Wo, W1, W2, user_emb, ws);
  compact_valid<<<dim3(160), dim3(256), 0, stream>>>(edges, u_mask, ws);

  if (emb16)
    attend<0,true><<<dim3(NSLOT/G), dim3(256), 0, stream>>>(
        nodes, edges, tst, u_edges, u_neig, u_times, u_mask,
        i_neig, i_times, i_mask, user_emb, item_emb, time_w, time_b,
        bv, bo, b1, b2, ws, out);
  else
    attend<0,false><<<dim3(NSLOT/G), dim3(256), 0, stream>>>(
        nodes, edges, tst, u_edges, u_neig, u_times, u_mask,
        i_neig, i_times, i_mask, user_emb, item_emb, time_w, time_b,
        bv, bo, b1, b2, ws, out);

  attend<1,true><<<dim3(NB_B/G), dim3(256), 0, stream>>>(
      nodes, edges, tst, u_edges, u_neig, u_times, u_mask,
      i_neig, i_times, i_mask, user_emb, item_emb, time_w, time_b,
      bv, bo, b1, b2, ws, out);
}